// Round 12
// baseline (196.678 us; speedup 1.0000x reference)
//
#include <hip/hip_runtime.h>
#include <math.h>

// ============================================================================
// Cross-covariance transformer block.  Round 12 (= round 11, k_tail at
// launch_bounds(256,4)): r11 reduced arch-reg demand to 76 and AGPR to ~40
// (76+40=116 <= 128/wave at 4 blocks/CU), so the 4-block config that spilled
// in r6/r7 (demand was >128 then) should now fit spill-free.  k_tail is
// memory-latency bound (HBM 1.28 TB/s of 6.3, nothing saturated, occ 29%);
// occupancy 3->4 blocks/CU is the latency-hiding lever.
// Single-variable experiment: everything else identical to round 11.
// ============================================================================

typedef __bf16 bf16x8 __attribute__((ext_vector_type(8)));
typedef float f32x4 __attribute__((ext_vector_type(4)));
typedef unsigned short u16x8 __attribute__((ext_vector_type(8)));
typedef unsigned int u32x2 __attribute__((ext_vector_type(2)));
typedef unsigned int u32x4 __attribute__((ext_vector_type(4)));
typedef unsigned short ushort_t;

static constexpr int  DM   = 128;
static constexpr long NTOK = 131072;                 // B*S = 32*4096
static constexpr float NORMF = 0.17677669529663687f; // 1/sqrt(32)

__device__ __forceinline__ unsigned short f2b(float x) {
    __bf16 b = (__bf16)x;
    return __builtin_bit_cast(unsigned short, b);
}
__device__ __forceinline__ float b2f(unsigned short h) {
    return __builtin_bit_cast(float, ((unsigned)h) << 16);
}
__device__ __forceinline__ float b2f_lo(unsigned u) {
    return __builtin_bit_cast(float, u << 16);
}
__device__ __forceinline__ float b2f_hi(unsigned u) {
    return __builtin_bit_cast(float, u & 0xffff0000u);
}
__device__ __forceinline__ unsigned pack2(float a, float b) {
    return (unsigned)f2b(a) | ((unsigned)f2b(b) << 16);
}
__device__ __forceinline__ f32x4 mfma16(bf16x8 a, bf16x8 b, f32x4 c) {
    return __builtin_amdgcn_mfma_f32_16x16x32_bf16(a, b, c, 0, 0, 0);
}
// [64][128] bf16 tile, 16B chunks XOR-swizzled by tok&7
__device__ __forceinline__ int xb_off(int tok, int chunk) {
    int c = (chunk & 8) | ((chunk ^ tok) & 7);
    return tok * 128 + c * 8;
}
// tanh-form gelu
__device__ __forceinline__ float gelu_f(float x) {
    float x2 = x * x;
    float y = -x * fmaf(0.0713548162f, x2, 1.5957691216f);
    float e = __expf(y);
    return x * __builtin_amdgcn_rcpf(1.0f + e);
}

// ---------------------------------------------------------------------------
// k_wcvt: weights -> MFMA-A-fragment-linear bf16.  W1t is ln_g-folded.
// ---------------------------------------------------------------------------
__global__ __launch_bounds__(256)
void k_wcvt(const float* __restrict__ W1, const float* __restrict__ W2,
            const float* __restrict__ Wo, const float* __restrict__ Wq,
            const float* __restrict__ Wk, const float* __restrict__ Wv,
            const float* __restrict__ lng,
            ushort_t* __restrict__ W1t, ushort_t* __restrict__ W2t,
            ushort_t* __restrict__ Wot,
            ushort_t* __restrict__ Wqh, ushort_t* __restrict__ Wql,
            ushort_t* __restrict__ Wkh, ushort_t* __restrict__ Wkl,
            ushort_t* __restrict__ Wvh, ushort_t* __restrict__ Wvl)
{
    int frag = blockIdx.x * 4 + (threadIdx.x >> 6);
    int l = threadIdx.x & 63;
    int lr = l & 15, lg = l >> 4;
    u16x8 v;
    if (frag < 128) {                       // W1t (g-folded): 32 ht x 4 ks
        int ht = frag >> 2, ks = frag & 3;
        #pragma unroll
        for (int j = 0; j < 8; ++j) {
            int k = ks * 32 + lg * 8 + j;
            v[j] = f2b(lng[k] * W1[(long)k * 512 + ht * 16 + lr]);
        }
        *(u16x8*)(W1t + ((long)frag * 64 + l) * 8) = v;
    } else if (frag < 256) {                // W2t: 8 oc-tiles x 16 k-steps
        int f = frag - 128;
        int ot = f >> 4, ks = f & 15;
        #pragma unroll
        for (int j = 0; j < 8; ++j)
            v[j] = f2b(W2[(ks * 32 + lg * 8 + j) * 128 + ot * 16 + lr]);
        *(u16x8*)(W2t + ((long)f * 64 + l) * 8) = v;
    } else if (frag < 288) {                // Wot: 8 oc-tiles x 4 k-steps
        int f = frag - 256;
        int ot = f >> 2, ks = f & 3;
        #pragma unroll
        for (int j = 0; j < 8; ++j)
            v[j] = f2b(Wo[(ks * 32 + lg * 8 + j) * 128 + ot * 16 + lr]);
        *(u16x8*)(Wot + ((long)f * 64 + l) * 8) = v;
    } else {                                // Wq/Wk/Wv hi+lo, 32 frags each
        int f = frag - 288;
        const float* S = (f < 32) ? Wq : (f < 64) ? Wk : Wv;
        ushort_t* dh = (f < 32) ? Wqh : (f < 64) ? Wkh : Wvh;
        ushort_t* dl = (f < 32) ? Wql : (f < 64) ? Wkl : Wvl;
        int fl = f & 31, ot = fl >> 2, ks = fl & 3;
        u16x8 vh, vl;
        #pragma unroll
        for (int j = 0; j < 8; ++j) {
            float x = S[(ks * 32 + lg * 8 + j) * 128 + ot * 16 + lr];
            __bf16 bh = (__bf16)x;
            vh[j] = __builtin_bit_cast(unsigned short, bh);
            vl[j] = f2b(x - (float)bh);
        }
        *(u16x8*)(dh + ((long)fl * 64 + l) * 8) = vh;
        *(u16x8*)(dl + ((long)fl * 64 + l) * 8) = vl;
    }
}

// ---------------------------------------------------------------------------
// k_lnfold: G1[j] = sum_k lng[k]*W1[k][j];  C1[j] = sum_k lnb[k]*W1[k][j]+b1[j]
// ---------------------------------------------------------------------------
__global__ __launch_bounds__(256)
void k_lnfold(const float* __restrict__ W1, const float* __restrict__ lng,
              const float* __restrict__ lnb, const float* __restrict__ b1,
              float* __restrict__ G1, float* __restrict__ C1)
{
    int j = blockIdx.x * 256 + threadIdx.x;
    float gs = 0.f, bs = 0.f;
    for (int k = 0; k < 128; ++k) {
        float wv = W1[(long)k * 512 + j];
        gs = fmaf(lng[k], wv, gs);
        bs = fmaf(lnb[k], wv, bs);
    }
    G1[j] = gs;
    C1[j] = bs + b1[j];
}

// ---------------------------------------------------------------------------
// k_qkvs: 64 tokens/block.  Split-bf16 MFMA for Q (3-pass, from v), K
// (3-pass), V (1-pass, from q); 8-group normalize Q,K; partial scores.
// ---------------------------------------------------------------------------
__global__ __launch_bounds__(256, 2)
void k_qkvs(const float* __restrict__ qin, const float* __restrict__ vin,
            const ushort_t* __restrict__ Wqh, const ushort_t* __restrict__ Wql,
            const ushort_t* __restrict__ Wkh, const ushort_t* __restrict__ Wkl,
            const ushort_t* __restrict__ Wvh,
            const float* __restrict__ bq, const float* __restrict__ bk,
            const float* __restrict__ bv,
            ushort_t* __restrict__ Vbf, float* __restrict__ scoreacc)
{
    __shared__ __align__(16) char smem[65536];
    ushort_t* vhi = (ushort_t*)smem;            // [64][128] swz  (input v)
    ushort_t* vlo = vhi + 8192;
    ushort_t* qhi = vlo + 8192;                 // (input q)
    ushort_t* qlo = qhi + 8192;
    ushort_t* Vt  = (ushort_t*)smem;            // alias (16 KB) after phases
    float*    red = (float*)(smem + 16384);     // [16][33] alias

    const int tid = threadIdx.x;
    const int w = tid >> 6, l = tid & 63;
    const int lr = l & 15, lg = l >> 4;
    const long tok0 = (long)blockIdx.x * 64;

    // ---- stage inputs, split hi/lo ----
    #pragma unroll
    for (int i = 0; i < 4; ++i) {
        int e = tid + i * 256;
        int tok = e >> 4, c = e & 15;
        long base = (tok0 + tok) * DM + c * 8;
        int xo = xb_off(tok, c);
        {
            float4 a0 = *(const float4*)(vin + base);
            float4 a1 = *(const float4*)(vin + base + 4);
            float xs[8] = {a0.x, a0.y, a0.z, a0.w, a1.x, a1.y, a1.z, a1.w};
            u16x8 hi, lo;
            #pragma unroll
            for (int jj = 0; jj < 8; ++jj) {
                __bf16 bh = (__bf16)xs[jj];
                hi[jj] = __builtin_bit_cast(unsigned short, bh);
                lo[jj] = f2b(xs[jj] - (float)bh);
            }
            *(u16x8*)(vhi + xo) = hi;
            *(u16x8*)(vlo + xo) = lo;
        }
        {
            float4 a0 = *(const float4*)(qin + base);
            float4 a1 = *(const float4*)(qin + base + 4);
            float xs[8] = {a0.x, a0.y, a0.z, a0.w, a1.x, a1.y, a1.z, a1.w};
            u16x8 hi, lo;
            #pragma unroll
            for (int jj = 0; jj < 8; ++jj) {
                __bf16 bh = (__bf16)xs[jj];
                hi[jj] = __builtin_bit_cast(unsigned short, bh);
                lo[jj] = f2b(xs[jj] - (float)bh);
            }
            *(u16x8*)(qhi + xo) = hi;
            *(u16x8*)(qlo + xo) = lo;
        }
    }
    __syncthreads();

    // ---- Q phase (input v) ----
    float qv[2][4][4];
    {
        f32x4 acc[2][4];
        #pragma unroll
        for (int ot = 0; ot < 2; ++ot)
            #pragma unroll
            for (int tt = 0; tt < 4; ++tt) acc[ot][tt] = (f32x4){0,0,0,0};
        #pragma unroll
        for (int ks = 0; ks < 4; ++ks) {
            bf16x8 wh[2], wl[2];
            #pragma unroll
            for (int ot = 0; ot < 2; ++ot) {
                int fi = (((w * 2 + ot) * 4 + ks) * 64 + l) * 8;
                wh[ot] = *(const bf16x8*)(Wqh + fi);
                wl[ot] = *(const bf16x8*)(Wql + fi);
            }
            #pragma unroll
            for (int tt = 0; tt < 4; ++tt) {
                int xo = xb_off(tt * 16 + lr, ks * 4 + lg);
                bf16x8 xh = *(const bf16x8*)(vhi + xo);
                bf16x8 xl = *(const bf16x8*)(vlo + xo);
                #pragma unroll
                for (int ot = 0; ot < 2; ++ot) {
                    acc[ot][tt] = mfma16(wh[ot], xh, acc[ot][tt]);
                    acc[ot][tt] = mfma16(wh[ot], xl, acc[ot][tt]);
                    acc[ot][tt] = mfma16(wl[ot], xh, acc[ot][tt]);
                }
            }
        }
        #pragma unroll
        for (int ot = 0; ot < 2; ++ot) {
            f32x4 bqv = *(const f32x4*)(bq + w * 32 + ot * 16 + lg * 4);
            #pragma unroll
            for (int tt = 0; tt < 4; ++tt) {
                float s2 = 0.f;
                #pragma unroll
                for (int r = 0; r < 4; ++r) {
                    float x = acc[ot][tt][r] + bqv[r];
                    qv[ot][tt][r] = x;
                    s2 = fmaf(x, x, s2);
                }
                s2 += __shfl_xor(s2, 16);
                float inv = 1.0f / fmaxf(sqrtf(s2), 1e-12f);
                #pragma unroll
                for (int r = 0; r < 4; ++r) qv[ot][tt][r] *= inv;
            }
        }
    }

    // ---- K (3-pass) + V (1-pass) + incremental score accumulation ----
    float vv[2][4][4];
    float part[4][8];
    #pragma unroll
    for (int r = 0; r < 4; ++r)
        #pragma unroll
        for (int e = 0; e < 8; ++e) part[r][e] = 0.f;
    {
        f32x4 acck[2][4], accv[2][4];
        #pragma unroll
        for (int ot = 0; ot < 2; ++ot)
            #pragma unroll
            for (int tt = 0; tt < 4; ++tt) {
                acck[ot][tt] = (f32x4){0,0,0,0};
                accv[ot][tt] = (f32x4){0,0,0,0};
            }
        #pragma unroll
        for (int ks = 0; ks < 4; ++ks) {
            bf16x8 whk[2], wlk[2], whv[2];
            #pragma unroll
            for (int ot = 0; ot < 2; ++ot) {
                int fi = (((w * 2 + ot) * 4 + ks) * 64 + l) * 8;
                whk[ot] = *(const bf16x8*)(Wkh + fi);
                wlk[ot] = *(const bf16x8*)(Wkl + fi);
                whv[ot] = *(const bf16x8*)(Wvh + fi);
            }
            #pragma unroll
            for (int tt = 0; tt < 4; ++tt) {
                int xo = xb_off(tt * 16 + lr, ks * 4 + lg);
                bf16x8 xh = *(const bf16x8*)(qhi + xo);
                bf16x8 xl = *(const bf16x8*)(qlo + xo);
                #pragma unroll
                for (int ot = 0; ot < 2; ++ot) {
                    acck[ot][tt] = mfma16(whk[ot], xh, acck[ot][tt]);
                    acck[ot][tt] = mfma16(whk[ot], xl, acck[ot][tt]);
                    acck[ot][tt] = mfma16(wlk[ot], xh, acck[ot][tt]);
                    accv[ot][tt] = mfma16(whv[ot], xh, accv[ot][tt]);
                }
            }
        }
        const int h0 = (lg & 1) * 4;
        #pragma unroll
        for (int ot = 0; ot < 2; ++ot) {
            f32x4 bkv = *(const f32x4*)(bk + w * 32 + ot * 16 + lg * 4);
            f32x4 bvv = *(const f32x4*)(bv + w * 32 + ot * 16 + lg * 4);
            #pragma unroll
            for (int tt = 0; tt < 4; ++tt) {
                float kq[4];
                float s2 = 0.f;
                #pragma unroll
                for (int r = 0; r < 4; ++r) {
                    float x = acck[ot][tt][r] + bkv[r];
                    kq[r] = x;
                    s2 = fmaf(x, x, s2);
                    vv[ot][tt][r] = accv[ot][tt][r] + bvv[r];
                }
                s2 += __shfl_xor(s2, 16);
                float inv = 1.0f / fmaxf(sqrtf(s2), 1e-12f);
                #pragma unroll
                for (int r = 0; r < 4; ++r) kq[r] *= inv;
                float ko[4];
                #pragma unroll
                for (int r = 0; r < 4; ++r) ko[r] = __shfl_xor(kq[r], 16);
                float ke[8];
                #pragma unroll
                for (int r = 0; r < 4; ++r) {
                    ke[h0 + r] = kq[r];
                    ke[(h0 ^ 4) + r] = ko[r];
                }
                #pragma unroll
                for (int r = 0; r < 4; ++r)
                    #pragma unroll
                    for (int e = 0; e < 8; ++e)
                        part[r][e] = fmaf(qv[ot][tt][r], ke[e], part[r][e]);
            }
        }
    }
    // reduce partials over lr lanes (bits 0..3)
    #pragma unroll
    for (int r = 0; r < 4; ++r)
        #pragma unroll
        for (int e = 0; e < 8; ++e) {
            float p = part[r][e];
            p += __shfl_xor(p, 1);
            p += __shfl_xor(p, 2);
            p += __shfl_xor(p, 4);
            p += __shfl_xor(p, 8);
            part[r][e] = p;
        }
    __syncthreads();   // x-tiles fully consumed; alias regions now writable

    // V regs -> Vt (swizzled bf16 [64][128])
    #pragma unroll
    for (int ot = 0; ot < 2; ++ot) {
        int oc0 = w * 32 + ot * 16 + lg * 4;
        int ch = oc0 >> 3;
        #pragma unroll
        for (int tt = 0; tt < 4; ++tt) {
            int tok = tt * 16 + lr;
            int cz = (ch & 8) | ((ch ^ tok) & 7);
            u32x2 pk = {pack2(vv[ot][tt][0], vv[ot][tt][1]),
                        pack2(vv[ot][tt][2], vv[ot][tt][3])};
            *(u32x2*)(Vt + tok * 128 + cz * 8 + (oc0 & 7)) = pk;
        }
    }
    if (lr == 0) {
        #pragma unroll
        for (int r = 0; r < 4; ++r)
            #pragma unroll
            for (int e = 0; e < 8; ++e)
                red[(w * 4 + lg) * 33 + r * 8 + e] = part[r][e];
    }
    __syncthreads();

    // coalesced V store
    #pragma unroll
    for (int i = 0; i < 4; ++i) {
        int e = tid + i * 256;
        int tok = e >> 4, c = e & 15;
        int cz = (c & 8) | ((c ^ tok) & 7);
        u16x8 val = *(const u16x8*)(Vt + tok * 128 + cz * 8);
        *(u16x8*)(Vbf + (tok0 + tok) * DM + c * 8) = val;
    }
    if (tid < 64) {
        int d = tid >> 3, e = tid & 7;
        int par = d >> 2, r = d & 3;
        float s = 0.f;
        #pragma unroll
        for (int ww = 0; ww < 4; ++ww)
            s += red[(ww * 4 + par) * 33 + r * 8 + e] +
                 red[(ww * 4 + par + 2) * 33 + r * 8 + e];
        scoreacc[(long)blockIdx.x * 64 + tid] = s;
    }
}

// ---------------------------------------------------------------------------
// k_medsoft
// ---------------------------------------------------------------------------
__global__ __launch_bounds__(64)
void k_medsoft(const float* __restrict__ scoreacc, ushort_t* __restrict__ probsb)
{
    __shared__ float sc[64], pl[64];
    const int p = blockIdx.x, tid = threadIdx.x;
    const float* s0 = scoreacc + (long)p * 256;
    sc[tid] = (s0[tid] + s0[64 + tid] + s0[128 + tid] + s0[192 + tid]) * NORMF;
    __syncthreads();
    if (tid < 8) {
        float row[8], st[8];
        #pragma unroll
        for (int e = 0; e < 8; ++e) { row[e] = sc[tid * 8 + e]; st[e] = row[e]; }
        for (int a = 1; a < 8; ++a) {
            float v = st[a]; int b = a - 1;
            while (b >= 0 && st[b] > v) { st[b + 1] = st[b]; --b; }
            st[b + 1] = v;
        }
        float med = st[3];
        float mv[8]; float mx = -3.0e38f;
        #pragma unroll
        for (int e = 0; e < 8; ++e) {
            mv[e] = (row[e] - med > 0.f) ? row[e] : -1e30f;
            mx = fmaxf(mx, mv[e]);
        }
        float z = 0.f, ex[8];
        #pragma unroll
        for (int e = 0; e < 8; ++e) { ex[e] = expf(mv[e] - mx); z += ex[e]; }
        float iz = 1.f / z;
        #pragma unroll
        for (int e = 0; e < 8; ++e) pl[tid * 8 + e] = ex[e] * iz;
    }
    __syncthreads();
    probsb[(long)p * 64 + tid] = f2b(pl[tid]);
}

// ---------------------------------------------------------------------------
// k_tail: fused AO-gather + Wo + LN1(folded) + FFN + LN2 + v.  64 tok2/block.
// (256,4): arch 76 + acc ~40 = 116 <= 128/wave -> spill-free 4 blocks/CU.
// ---------------------------------------------------------------------------
__global__ __launch_bounds__(256, 4)
void k_tail(const ushort_t* __restrict__ Vbf, const ushort_t* __restrict__ Pb,
            const ushort_t* __restrict__ Wot, const float* __restrict__ bo,
            const ushort_t* __restrict__ W1t, const float* __restrict__ G1,
            const float* __restrict__ C1,
            const ushort_t* __restrict__ W2t, const float* __restrict__ b2,
            const float* __restrict__ lng, const float* __restrict__ lnb,
            const float* __restrict__ vres, float* __restrict__ out)
{
    __shared__ __align__(16) char smem[35840];
    ushort_t* Xb  = (ushort_t*)smem;                 // attn tile -> FFN Hid
    ushort_t* Vg  = (ushort_t*)(smem + 16384);       // V gather -> h' (Hp)
    ushort_t* Hp  = (ushort_t*)(smem + 16384);
    float* pS   = (float*)(smem + 32768);            // 1 KB
    float* pQ   = (float*)(smem + 33792);            // 1 KB
    float* mu1S = (float*)(smem + 34816);            // 256 B
    float* rs1S = (float*)(smem + 35072);
    float* mu2S = (float*)(smem + 35328);
    float* rs2S = (float*)(smem + 35584);

    const int tid = threadIdx.x;
    const int w = tid >> 6, l = tid & 63;
    const int lr = l & 15, lg = l >> 4;
    const int wid = ((blockIdx.x & 7) << 8) | (blockIdx.x >> 3);
    const long T0 = (long)wid * 64;
    const int g  = (int)(T0 >> 13);
    const int r0 = (int)((T0 & 8191) >> 5);

    // ---- gather the 64 V rows ----
    #pragma unroll
    for (int i = 0; i < 4; ++i) {
        int e = tid + i * 256;
        int ri = e >> 4, c = e & 15;
        int hb = ri >> 5, bm = (ri >> 1) & 15, rr = ri & 1;
        long t = ((long)(g * 32 + hb * 16 + bm)) * 256 + r0 + rr;
        u16x8 val = *(const u16x8*)(Vbf + t * DM + c * 8);
        int cz = (c & 8) | ((c ^ (ri >> 1)) & 7);
        *(u16x8*)(Vg + ri * 128 + cz * 8) = val;
    }
    __syncthreads();

    // ---- AO -> Xb (bf16 swz); probs read from global (L1/L2-hot 4KB) ----
    #pragma unroll
    for (int i = 0; i < 4; ++i) {
        int e = tid + i * 256;
        int ti = e >> 4, bm = e & 15;
        int jj = (ti & 31) >> 1, hb = ti & 1, rr = ti >> 5;
        int ri = hb * 32 + bm * 2 + rr;
        int cz = (jj & 8) | ((jj ^ (ri >> 1)) & 7);
        u16x8 v8 = *(const u16x8*)(Vg + ri * 128 + cz * 8);
        float vf[8];
        #pragma unroll
        for (int e2 = 0; e2 < 8; ++e2) vf[e2] = b2f(v8[e2]);
        const ushort_t* pp = Pb + ((long)g * 32 + hb * 16 + bm) * 64;
        float sd[8];
        #pragma unroll
        for (int d = 0; d < 8; ++d) {
            u16x8 pr = *(const u16x8*)(pp + d * 8);
            float s = 0.f;
            #pragma unroll
            for (int e2 = 0; e2 < 8; ++e2) s = fmaf(b2f(pr[e2]), vf[e2], s);
            sd[d] = s;
        }
        u32x4 po = {pack2(sd[0], sd[1]), pack2(sd[2], sd[3]),
                    pack2(sd[4], sd[5]), pack2(sd[6], sd[7])};
        *(u32x4*)(Xb + xb_off(ti, bm)) = po;
    }
    __syncthreads();

    // ---- Wo GEMM (+ residual): h' -> Hp (bf16), stats in regs.
    //      tt-outer: bfrag[4] read once, feeds both ot chains. ----
    float sums[4] = {0, 0, 0, 0}, sqs[4] = {0, 0, 0, 0};
    {
        bf16x8 aw[2][4];
        #pragma unroll
        for (int ot = 0; ot < 2; ++ot)
            #pragma unroll
            for (int ks = 0; ks < 4; ++ks)
                aw[ot][ks] = *(const bf16x8*)(Wot +
                    ((long)((w * 2 + ot) * 4 + ks) * 64 + l) * 8);
        f32x4 bov[2];
        #pragma unroll
        for (int ot = 0; ot < 2; ++ot)
            bov[ot] = *(const f32x4*)(bo + w * 32 + ot * 16 + lg * 4);

        #pragma unroll
        for (int tt = 0; tt < 4; ++tt) {
            int tok = tt * 16 + lr;
            bf16x8 bfr[4];
            #pragma unroll
            for (int ks = 0; ks < 4; ++ks)
                bfr[ks] = *(const bf16x8*)(Xb + xb_off(tok, ks * 4 + lg));
            f32x4 acc[2] = {(f32x4){0,0,0,0}, (f32x4){0,0,0,0}};
            #pragma unroll
            for (int ks = 0; ks < 4; ++ks) {
                acc[0] = mfma16(aw[0][ks], bfr[ks], acc[0]);
                acc[1] = mfma16(aw[1][ks], bfr[ks], acc[1]);
            }
            long gtok = T0 + tok;
            #pragma unroll
            for (int ot = 0; ot < 2; ++ot) {
                int oc0 = w * 32 + ot * 16 + lg * 4;
                f32x4 xv = *(const f32x4*)(vres + gtok * DM + oc0);
                float hp[4];
                #pragma unroll
                for (int r = 0; r < 4; ++r) {
                    hp[r] = acc[ot][r] + bov[ot][r] + xv[r];
                    sums[tt] += hp[r];
                    sqs[tt] = fmaf(hp[r], hp[r], sqs[tt]);
                }
                int ch = oc0 >> 3;
                int cz = (ch & 8) | ((ch ^ tok) & 7);
                u32x2 pk = {pack2(hp[0], hp[1]), pack2(hp[2], hp[3])};
                *(u32x2*)(Hp + tok * 128 + cz * 8 + (oc0 & 7)) = pk;
            }
        }
    }
    #pragma unroll
    for (int tt = 0; tt < 4; ++tt) {
        sums[tt] += __shfl_xor(sums[tt], 16);
        sums[tt] += __shfl_xor(sums[tt], 32);
        sqs[tt]  += __shfl_xor(sqs[tt], 16);
        sqs[tt]  += __shfl_xor(sqs[tt], 32);
    }
    #pragma unroll
    for (int tt = 0; tt < 4; ++tt)
        if (lg == tt) { pS[(w * 4 + tt) * 16 + lr] = sums[tt];
                        pQ[(w * 4 + tt) * 16 + lr] = sqs[tt]; }
    __syncthreads();
    if (tid < 64) {
        float s = pS[tid] + pS[64 + tid] + pS[128 + tid] + pS[192 + tid];
        float q = pQ[tid] + pQ[64 + tid] + pQ[128 + tid] + pQ[192 + tid];
        float mu = s * 0.0078125f;
        float var = q * 0.0078125f - mu * mu;
        mu1S[tid] = mu;
        rs1S[tid] = rsqrtf(var + 1e-5f);
    }
    __syncthreads();

    // ---- FFN: 4 hidden slices of 128; stage1 reads h' and applies folded LN
    f32x4 oacc[4][2];
    #pragma unroll
    for (int tt = 0; tt < 4; ++tt) {
        oacc[tt][0] = (f32x4){0,0,0,0};
        oacc[tt][1] = (f32x4){0,0,0,0};
    }
    for (int sl = 0; sl < 4; ++sl) {
        // stage 1: tt-outer, bfrag[4] from Hp feeds both hh chains
        {
            bf16x8 a1[2][4];
            f32x4 G1v[2], C1v[2];
            #pragma unroll
            for (int hh = 0; hh < 2; ++hh) {
                #pragma unroll
                for (int ks = 0; ks < 4; ++ks)
                    a1[hh][ks] = *(const bf16x8*)(W1t +
                        ((long)((sl * 8 + w * 2 + hh) * 4 + ks) * 64 + l) * 8);
                int hcb = (sl * 8 + w * 2 + hh) * 16 + lg * 4;
                G1v[hh] = *(const f32x4*)(G1 + hcb);
                C1v[hh] = *(const f32x4*)(C1 + hcb);
            }
            #pragma unroll
            for (int tt = 0; tt < 4; ++tt) {
                int tok = tt * 16 + lr;
                bf16x8 bfr[4];
                #pragma unroll
                for (int ks = 0; ks < 4; ++ks)
                    bfr[ks] = *(const bf16x8*)(Hp + xb_off(tok, ks * 4 + lg));
                f32x4 acc[2] = {(f32x4){0,0,0,0}, (f32x4){0,0,0,0}};
                #pragma unroll
                for (int ks = 0; ks < 4; ++ks) {
                    acc[0] = mfma16(a1[0][ks], bfr[ks], acc[0]);
                    acc[1] = mfma16(a1[1][ks], bfr[ks], acc[1]);
                }
                float mu1 = mu1S[tok], rs1 = rs1S[tok];
                float mneg = -mu1 * rs1;
                #pragma unroll
                for (int hh = 0; hh < 2; ++hh) {
                    float gg[4];
                    #pragma unroll
                    for (int r = 0; r < 4; ++r) {
                        float pre = fmaf(rs1, acc[hh][r],
                                         fmaf(mneg, G1v[hh][r], C1v[hh][r]));
                        gg[r] = gelu_f(pre);
                    }
                    int hc0 = w * 32 + hh * 16 + lg * 4;
                    int ch = hc0 >> 3;
                    int cz = (ch & 8) | ((ch ^ tok) & 7);
                    u32x2 pk = {pack2(gg[0], gg[1]), pack2(gg[2], gg[3])};
                    *(u32x2*)(Xb + tok * 128 + cz * 8 + (hc0 & 7)) = pk;
                }
            }
        }
        __syncthreads();
        // stage 2: tt-outer, bfrag[4] from Xb feeds both op accumulators
        {
            bf16x8 a2[2][4];
            #pragma unroll
            for (int op = 0; op < 2; ++op)
                #pragma unroll
                for (int kl = 0; kl < 4; ++kl)
                    a2[op][kl] = *(const bf16x8*)(W2t +
                        ((long)((w * 2 + op) * 16 + sl * 4 + kl) * 64 + l) * 8);
            #pragma unroll
            for (int tt = 0; tt < 4; ++tt) {
                int tok = tt * 16 + lr;
                bf16x8 bfr[4];
                #pragma unroll
                for (int kl = 0; kl < 4; ++kl)
                    bfr[kl] = *(const bf16x8*)(Xb + xb_off(tok, kl * 4 + lg));
                #pragma unroll
                for (int kl = 0; kl < 4; ++kl) {
                    oacc[tt][0] = mfma16(a2[0][kl], bfr[kl], oacc[tt][0]);
                    oacc[tt][1] = mfma16(a2[1][kl], bfr[kl], oacc[tt][1]);
                }
            }
        }
        __syncthreads();
    }

    // ---- LN2: vvv = oacc + b2 + h, h = LN1-affine(h' from Hp) ----
    #pragma unroll
    for (int tt = 0; tt < 4; ++tt) {
        int tok = tt * 16 + lr;
        float mu1 = mu1S[tok], rs1 = rs1S[tok];
        float s = 0.f, q = 0.f;
        #pragma unroll
        for (int ot = 0; ot < 2; ++ot) {
            int oc0 = w * 32 + ot * 16 + lg * 4;
            f32x4 b2v = *(const f32x4*)(b2 + oc0);
            f32x4 g4 = *(const f32x4*)(lng + oc0);
            f32x4 bb4 = *(const f32x4*)(lnb + oc0);
            int ch = oc0 >> 3;
            int cz = (ch & 8) | ((ch ^ tok) & 7);
            u32x2 hpv = *(const u32x2*)(Hp + tok * 128 + cz * 8 + (oc0 & 7));
            float hr[4] = {b2f_lo(hpv[0]), b2f_hi(hpv[0]),
                           b2f_lo(hpv[1]), b2f_hi(hpv[1])};
            #pragma unroll
            for (int r = 0; r < 4; ++r) {
                float h = (hr[r] - mu1) * rs1 * g4[r] + bb4[r];
                float vvv = oacc[tt][ot][r] + b2v[r] + h;
                s += vvv; q = fmaf(vvv, vvv, q);
            }
        }
        sums[tt] = s; sqs[tt] = q;
    }
    #pragma unroll
    for (int tt = 0; tt < 4; ++tt) {
        sums[tt] += __shfl_xor(sums[tt], 16);
        sums[tt] += __shfl_xor(sums[tt], 32);
        sqs[tt]  += __shfl_xor(sqs[tt], 16);
        sqs[tt]  += __shfl_xor(sqs[tt], 32);
    }
    #pragma unroll
    for (int tt = 0; tt < 4; ++tt)
        if (lg == tt) { pS[(w * 4 + tt) * 16 + lr] = sums[tt];
                        pQ[(w * 4 + tt) * 16 + lr] = sqs[tt]; }
    __syncthreads();
    if (tid < 64) {
        float s = pS[tid] + pS[64 + tid] + pS[128 + tid] + pS[192 + tid];
        float q = pQ[tid] + pQ[64 + tid] + pQ[128 + tid] + pQ[192 + tid];
        float mu = s * 0.0078125f;
        float var = q * 0.0078125f - mu * mu;
        mu2S[tid] = mu;
        rs2S[tid] = rsqrtf(var + 1e-5f);
    }
    __syncthreads();
    #pragma unroll
    for (int tt = 0; tt < 4; ++tt) {
        int tok = tt * 16 + lr;
        long gtok = T0 + tok;
        float mu1 = mu1S[tok], rs1 = rs1S[tok];
        float mu2 = mu2S[tok], rs2 = rs2S[tok];
        #pragma unroll
        for (int ot = 0; ot < 2; ++ot) {
            int oc0 = w * 32 + ot * 16 + lg * 4;
            f32x4 b2v = *(const f32x4*)(b2 + oc0);
            f32x4 g4 = *(const f32x4*)(lng + oc0);
            f32x4 bb4 = *(const f32x4*)(lnb + oc0);
            int ch = oc0 >> 3;
            int cz = (ch & 8) | ((ch ^ tok) & 7);
            u32x2 hpv = *(const u32x2*)(Hp + tok * 128 + cz * 8 + (oc0 & 7));
            float hr[4] = {b2f_lo(hpv[0]), b2f_hi(hpv[0]),
                           b2f_lo(hpv[1]), b2f_hi(hpv[1])};
            f32x4 vv4 = *(const f32x4*)(vres + gtok * DM + oc0);
            f32x4 o;
            #pragma unroll
            for (int r = 0; r < 4; ++r) {
                float h = (hr[r] - mu1) * rs1 * g4[r] + bb4[r];
                float vvv = oacc[tt][ot][r] + b2v[r] + h;
                o[r] = (vvv - mu2) * rs2 * g4[r] + bb4[r] + vv4[r];
            }
            *(f32x4*)(out + gtok * DM + oc0) = o;
        }
    }
}

// ---------------------------------------------------------------------------
extern "C" void kernel_launch(void* const* d_in, const int* in_sizes, int n_in,
                              void* d_out, int out_size, void* d_ws, size_t ws_size,
                              hipStream_t stream)
{
    const float* q   = (const float*)d_in[0];
    const float* v   = (const float*)d_in[1];
    const float* Wq  = (const float*)d_in[2];
    const float* bq  = (const float*)d_in[3];
    const float* Wk  = (const float*)d_in[4];
    const float* bk  = (const float*)d_in[5];
    const float* Wv  = (const float*)d_in[6];
    const float* bv  = (const float*)d_in[7];
    const float* Wo  = (const float*)d_in[8];
    const float* bo  = (const float*)d_in[9];
    const float* lng = (const float*)d_in[10];
    const float* lnb = (const float*)d_in[11];
    const float* W1  = (const float*)d_in[12];
    const float* b1  = (const float*)d_in[13];
    const float* W2  = (const float*)d_in[14];
    const float* b2  = (const float*)d_in[15];
    float* out = (float*)d_out;

    char* W = (char*)d_ws;
    ushort_t* Vbf      = (ushort_t*)(W);               // 32 MB
    float*    scoreacc = (float*)(W + 33554432);       // 512 KB
    ushort_t* probsb   = (ushort_t*)(W + 34078720);    // 64 KB (bf16)
    char* wbase = W + 34209792;
    ushort_t* Wqh = (ushort_t*)(wbase);
    ushort_t* Wql = (ushort_t*)(wbase + 32768);
    ushort_t* Wkh = (ushort_t*)(wbase + 65536);
    ushort_t* Wkl = (ushort_t*)(wbase + 98304);
    ushort_t* Wvh = (ushort_t*)(wbase + 131072);
    ushort_t* Wvl = (ushort_t*)(wbase + 163840);
    ushort_t* W1t = (ushort_t*)(wbase + 196608);       // 128 KB
    ushort_t* W2t = (ushort_t*)(wbase + 327680);       // 128 KB
    ushort_t* Wot = (ushort_t*)(wbase + 458752);       // 32 KB
    float*    G1  = (float*)(wbase + 491520);          // 2 KB
    float*    C1  = (float*)(wbase + 493568);          // 2 KB

    dim3 blk(256);
    k_wcvt<<<96, blk, 0, stream>>>(W1, W2, Wo, Wq, Wk, Wv, lng,
                                   W1t, W2t, Wot, Wqh, Wql, Wkh, Wkl, Wvh, Wvl);
    k_lnfold<<<2, blk, 0, stream>>>(W1, lng, lnb, b1, G1, C1);
    k_qkvs<<<2048, blk, 0, stream>>>(q, v, Wqh, Wql, Wkh, Wkl, Wvh,
                                     bq, bk, bv, Vbf, scoreacc);
    k_medsoft<<<512, dim3(64), 0, stream>>>(scoreacc, probsb);
    k_tail<<<2048, blk, 0, stream>>>(Vbf, probsb, Wot, bo, W1t, G1, C1,
                                     W2t, b2, lng, lnb, v, out);
}

// Round 13
// 190.646 us; speedup vs baseline: 1.0316x; 1.0316x over previous
//
#include <hip/hip_runtime.h>
#include <math.h>

// ============================================================================
// Cross-covariance transformer block.  Round 13 (= round 11 + T14 in k_tail):
//  - launch_bounds back to (256,3) -- (256,4) provably forces the 64/64
//    unified-file split + ~64MB spill (r6/r7/r12, VGPR pinned at 64).
//  - T14 issue-early: all 8 vres f32x4 loads issued at kernel start (HBM
//    latency hides under the AO phase), held in regs, reused in the LN2
//    epilogue (second vres read pass deleted).  Wo weight fragments
//    prefetched before the first barrier.  Arch demand ~112 < 170 cap.
// ============================================================================

typedef __bf16 bf16x8 __attribute__((ext_vector_type(8)));
typedef float f32x4 __attribute__((ext_vector_type(4)));
typedef unsigned short u16x8 __attribute__((ext_vector_type(8)));
typedef unsigned int u32x2 __attribute__((ext_vector_type(2)));
typedef unsigned int u32x4 __attribute__((ext_vector_type(4)));
typedef unsigned short ushort_t;

static constexpr int  DM   = 128;
static constexpr long NTOK = 131072;                 // B*S = 32*4096
static constexpr float NORMF = 0.17677669529663687f; // 1/sqrt(32)

__device__ __forceinline__ unsigned short f2b(float x) {
    __bf16 b = (__bf16)x;
    return __builtin_bit_cast(unsigned short, b);
}
__device__ __forceinline__ float b2f(unsigned short h) {
    return __builtin_bit_cast(float, ((unsigned)h) << 16);
}
__device__ __forceinline__ float b2f_lo(unsigned u) {
    return __builtin_bit_cast(float, u << 16);
}
__device__ __forceinline__ float b2f_hi(unsigned u) {
    return __builtin_bit_cast(float, u & 0xffff0000u);
}
__device__ __forceinline__ unsigned pack2(float a, float b) {
    return (unsigned)f2b(a) | ((unsigned)f2b(b) << 16);
}
__device__ __forceinline__ f32x4 mfma16(bf16x8 a, bf16x8 b, f32x4 c) {
    return __builtin_amdgcn_mfma_f32_16x16x32_bf16(a, b, c, 0, 0, 0);
}
// [64][128] bf16 tile, 16B chunks XOR-swizzled by tok&7
__device__ __forceinline__ int xb_off(int tok, int chunk) {
    int c = (chunk & 8) | ((chunk ^ tok) & 7);
    return tok * 128 + c * 8;
}
// tanh-form gelu
__device__ __forceinline__ float gelu_f(float x) {
    float x2 = x * x;
    float y = -x * fmaf(0.0713548162f, x2, 1.5957691216f);
    float e = __expf(y);
    return x * __builtin_amdgcn_rcpf(1.0f + e);
}

// ---------------------------------------------------------------------------
// k_wcvt: weights -> MFMA-A-fragment-linear bf16.  W1t is ln_g-folded.
// ---------------------------------------------------------------------------
__global__ __launch_bounds__(256)
void k_wcvt(const float* __restrict__ W1, const float* __restrict__ W2,
            const float* __restrict__ Wo, const float* __restrict__ Wq,
            const float* __restrict__ Wk, const float* __restrict__ Wv,
            const float* __restrict__ lng,
            ushort_t* __restrict__ W1t, ushort_t* __restrict__ W2t,
            ushort_t* __restrict__ Wot,
            ushort_t* __restrict__ Wqh, ushort_t* __restrict__ Wql,
            ushort_t* __restrict__ Wkh, ushort_t* __restrict__ Wkl,
            ushort_t* __restrict__ Wvh, ushort_t* __restrict__ Wvl)
{
    int frag = blockIdx.x * 4 + (threadIdx.x >> 6);
    int l = threadIdx.x & 63;
    int lr = l & 15, lg = l >> 4;
    u16x8 v;
    if (frag < 128) {                       // W1t (g-folded): 32 ht x 4 ks
        int ht = frag >> 2, ks = frag & 3;
        #pragma unroll
        for (int j = 0; j < 8; ++j) {
            int k = ks * 32 + lg * 8 + j;
            v[j] = f2b(lng[k] * W1[(long)k * 512 + ht * 16 + lr]);
        }
        *(u16x8*)(W1t + ((long)frag * 64 + l) * 8) = v;
    } else if (frag < 256) {                // W2t: 8 oc-tiles x 16 k-steps
        int f = frag - 128;
        int ot = f >> 4, ks = f & 15;
        #pragma unroll
        for (int j = 0; j < 8; ++j)
            v[j] = f2b(W2[(ks * 32 + lg * 8 + j) * 128 + ot * 16 + lr]);
        *(u16x8*)(W2t + ((long)f * 64 + l) * 8) = v;
    } else if (frag < 288) {                // Wot: 8 oc-tiles x 4 k-steps
        int f = frag - 256;
        int ot = f >> 2, ks = f & 3;
        #pragma unroll
        for (int j = 0; j < 8; ++j)
            v[j] = f2b(Wo[(ks * 32 + lg * 8 + j) * 128 + ot * 16 + lr]);
        *(u16x8*)(Wot + ((long)f * 64 + l) * 8) = v;
    } else {                                // Wq/Wk/Wv hi+lo, 32 frags each
        int f = frag - 288;
        const float* S = (f < 32) ? Wq : (f < 64) ? Wk : Wv;
        ushort_t* dh = (f < 32) ? Wqh : (f < 64) ? Wkh : Wvh;
        ushort_t* dl = (f < 32) ? Wql : (f < 64) ? Wkl : Wvl;
        int fl = f & 31, ot = fl >> 2, ks = fl & 3;
        u16x8 vh, vl;
        #pragma unroll
        for (int j = 0; j < 8; ++j) {
            float x = S[(ks * 32 + lg * 8 + j) * 128 + ot * 16 + lr];
            __bf16 bh = (__bf16)x;
            vh[j] = __builtin_bit_cast(unsigned short, bh);
            vl[j] = f2b(x - (float)bh);
        }
        *(u16x8*)(dh + ((long)fl * 64 + l) * 8) = vh;
        *(u16x8*)(dl + ((long)fl * 64 + l) * 8) = vl;
    }
}

// ---------------------------------------------------------------------------
// k_lnfold: G1[j] = sum_k lng[k]*W1[k][j];  C1[j] = sum_k lnb[k]*W1[k][j]+b1[j]
// ---------------------------------------------------------------------------
__global__ __launch_bounds__(256)
void k_lnfold(const float* __restrict__ W1, const float* __restrict__ lng,
              const float* __restrict__ lnb, const float* __restrict__ b1,
              float* __restrict__ G1, float* __restrict__ C1)
{
    int j = blockIdx.x * 256 + threadIdx.x;
    float gs = 0.f, bs = 0.f;
    for (int k = 0; k < 128; ++k) {
        float wv = W1[(long)k * 512 + j];
        gs = fmaf(lng[k], wv, gs);
        bs = fmaf(lnb[k], wv, bs);
    }
    G1[j] = gs;
    C1[j] = bs + b1[j];
}

// ---------------------------------------------------------------------------
// k_qkvs: 64 tokens/block.  Split-bf16 MFMA for Q (3-pass, from v), K
// (3-pass), V (1-pass, from q); 8-group normalize Q,K; partial scores.
// ---------------------------------------------------------------------------
__global__ __launch_bounds__(256, 2)
void k_qkvs(const float* __restrict__ qin, const float* __restrict__ vin,
            const ushort_t* __restrict__ Wqh, const ushort_t* __restrict__ Wql,
            const ushort_t* __restrict__ Wkh, const ushort_t* __restrict__ Wkl,
            const ushort_t* __restrict__ Wvh,
            const float* __restrict__ bq, const float* __restrict__ bk,
            const float* __restrict__ bv,
            ushort_t* __restrict__ Vbf, float* __restrict__ scoreacc)
{
    __shared__ __align__(16) char smem[65536];
    ushort_t* vhi = (ushort_t*)smem;            // [64][128] swz  (input v)
    ushort_t* vlo = vhi + 8192;
    ushort_t* qhi = vlo + 8192;                 // (input q)
    ushort_t* qlo = qhi + 8192;
    ushort_t* Vt  = (ushort_t*)smem;            // alias (16 KB) after phases
    float*    red = (float*)(smem + 16384);     // [16][33] alias

    const int tid = threadIdx.x;
    const int w = tid >> 6, l = tid & 63;
    const int lr = l & 15, lg = l >> 4;
    const long tok0 = (long)blockIdx.x * 64;

    // ---- stage inputs, split hi/lo ----
    #pragma unroll
    for (int i = 0; i < 4; ++i) {
        int e = tid + i * 256;
        int tok = e >> 4, c = e & 15;
        long base = (tok0 + tok) * DM + c * 8;
        int xo = xb_off(tok, c);
        {
            float4 a0 = *(const float4*)(vin + base);
            float4 a1 = *(const float4*)(vin + base + 4);
            float xs[8] = {a0.x, a0.y, a0.z, a0.w, a1.x, a1.y, a1.z, a1.w};
            u16x8 hi, lo;
            #pragma unroll
            for (int jj = 0; jj < 8; ++jj) {
                __bf16 bh = (__bf16)xs[jj];
                hi[jj] = __builtin_bit_cast(unsigned short, bh);
                lo[jj] = f2b(xs[jj] - (float)bh);
            }
            *(u16x8*)(vhi + xo) = hi;
            *(u16x8*)(vlo + xo) = lo;
        }
        {
            float4 a0 = *(const float4*)(qin + base);
            float4 a1 = *(const float4*)(qin + base + 4);
            float xs[8] = {a0.x, a0.y, a0.z, a0.w, a1.x, a1.y, a1.z, a1.w};
            u16x8 hi, lo;
            #pragma unroll
            for (int jj = 0; jj < 8; ++jj) {
                __bf16 bh = (__bf16)xs[jj];
                hi[jj] = __builtin_bit_cast(unsigned short, bh);
                lo[jj] = f2b(xs[jj] - (float)bh);
            }
            *(u16x8*)(qhi + xo) = hi;
            *(u16x8*)(qlo + xo) = lo;
        }
    }
    __syncthreads();

    // ---- Q phase (input v) ----
    float qv[2][4][4];
    {
        f32x4 acc[2][4];
        #pragma unroll
        for (int ot = 0; ot < 2; ++ot)
            #pragma unroll
            for (int tt = 0; tt < 4; ++tt) acc[ot][tt] = (f32x4){0,0,0,0};
        #pragma unroll
        for (int ks = 0; ks < 4; ++ks) {
            bf16x8 wh[2], wl[2];
            #pragma unroll
            for (int ot = 0; ot < 2; ++ot) {
                int fi = (((w * 2 + ot) * 4 + ks) * 64 + l) * 8;
                wh[ot] = *(const bf16x8*)(Wqh + fi);
                wl[ot] = *(const bf16x8*)(Wql + fi);
            }
            #pragma unroll
            for (int tt = 0; tt < 4; ++tt) {
                int xo = xb_off(tt * 16 + lr, ks * 4 + lg);
                bf16x8 xh = *(const bf16x8*)(vhi + xo);
                bf16x8 xl = *(const bf16x8*)(vlo + xo);
                #pragma unroll
                for (int ot = 0; ot < 2; ++ot) {
                    acc[ot][tt] = mfma16(wh[ot], xh, acc[ot][tt]);
                    acc[ot][tt] = mfma16(wh[ot], xl, acc[ot][tt]);
                    acc[ot][tt] = mfma16(wl[ot], xh, acc[ot][tt]);
                }
            }
        }
        #pragma unroll
        for (int ot = 0; ot < 2; ++ot) {
            f32x4 bqv = *(const f32x4*)(bq + w * 32 + ot * 16 + lg * 4);
            #pragma unroll
            for (int tt = 0; tt < 4; ++tt) {
                float s2 = 0.f;
                #pragma unroll
                for (int r = 0; r < 4; ++r) {
                    float x = acc[ot][tt][r] + bqv[r];
                    qv[ot][tt][r] = x;
                    s2 = fmaf(x, x, s2);
                }
                s2 += __shfl_xor(s2, 16);
                float inv = 1.0f / fmaxf(sqrtf(s2), 1e-12f);
                #pragma unroll
                for (int r = 0; r < 4; ++r) qv[ot][tt][r] *= inv;
            }
        }
    }

    // ---- K (3-pass) + V (1-pass) + incremental score accumulation ----
    float vv[2][4][4];
    float part[4][8];
    #pragma unroll
    for (int r = 0; r < 4; ++r)
        #pragma unroll
        for (int e = 0; e < 8; ++e) part[r][e] = 0.f;
    {
        f32x4 acck[2][4], accv[2][4];
        #pragma unroll
        for (int ot = 0; ot < 2; ++ot)
            #pragma unroll
            for (int tt = 0; tt < 4; ++tt) {
                acck[ot][tt] = (f32x4){0,0,0,0};
                accv[ot][tt] = (f32x4){0,0,0,0};
            }
        #pragma unroll
        for (int ks = 0; ks < 4; ++ks) {
            bf16x8 whk[2], wlk[2], whv[2];
            #pragma unroll
            for (int ot = 0; ot < 2; ++ot) {
                int fi = (((w * 2 + ot) * 4 + ks) * 64 + l) * 8;
                whk[ot] = *(const bf16x8*)(Wkh + fi);
                wlk[ot] = *(const bf16x8*)(Wkl + fi);
                whv[ot] = *(const bf16x8*)(Wvh + fi);
            }
            #pragma unroll
            for (int tt = 0; tt < 4; ++tt) {
                int xo = xb_off(tt * 16 + lr, ks * 4 + lg);
                bf16x8 xh = *(const bf16x8*)(qhi + xo);
                bf16x8 xl = *(const bf16x8*)(qlo + xo);
                #pragma unroll
                for (int ot = 0; ot < 2; ++ot) {
                    acck[ot][tt] = mfma16(whk[ot], xh, acck[ot][tt]);
                    acck[ot][tt] = mfma16(whk[ot], xl, acck[ot][tt]);
                    acck[ot][tt] = mfma16(wlk[ot], xh, acck[ot][tt]);
                    accv[ot][tt] = mfma16(whv[ot], xh, accv[ot][tt]);
                }
            }
        }
        const int h0 = (lg & 1) * 4;
        #pragma unroll
        for (int ot = 0; ot < 2; ++ot) {
            f32x4 bkv = *(const f32x4*)(bk + w * 32 + ot * 16 + lg * 4);
            f32x4 bvv = *(const f32x4*)(bv + w * 32 + ot * 16 + lg * 4);
            #pragma unroll
            for (int tt = 0; tt < 4; ++tt) {
                float kq[4];
                float s2 = 0.f;
                #pragma unroll
                for (int r = 0; r < 4; ++r) {
                    float x = acck[ot][tt][r] + bkv[r];
                    kq[r] = x;
                    s2 = fmaf(x, x, s2);
                    vv[ot][tt][r] = accv[ot][tt][r] + bvv[r];
                }
                s2 += __shfl_xor(s2, 16);
                float inv = 1.0f / fmaxf(sqrtf(s2), 1e-12f);
                #pragma unroll
                for (int r = 0; r < 4; ++r) kq[r] *= inv;
                float ko[4];
                #pragma unroll
                for (int r = 0; r < 4; ++r) ko[r] = __shfl_xor(kq[r], 16);
                float ke[8];
                #pragma unroll
                for (int r = 0; r < 4; ++r) {
                    ke[h0 + r] = kq[r];
                    ke[(h0 ^ 4) + r] = ko[r];
                }
                #pragma unroll
                for (int r = 0; r < 4; ++r)
                    #pragma unroll
                    for (int e = 0; e < 8; ++e)
                        part[r][e] = fmaf(qv[ot][tt][r], ke[e], part[r][e]);
            }
        }
    }
    // reduce partials over lr lanes (bits 0..3)
    #pragma unroll
    for (int r = 0; r < 4; ++r)
        #pragma unroll
        for (int e = 0; e < 8; ++e) {
            float p = part[r][e];
            p += __shfl_xor(p, 1);
            p += __shfl_xor(p, 2);
            p += __shfl_xor(p, 4);
            p += __shfl_xor(p, 8);
            part[r][e] = p;
        }
    __syncthreads();   // x-tiles fully consumed; alias regions now writable

    // V regs -> Vt (swizzled bf16 [64][128])
    #pragma unroll
    for (int ot = 0; ot < 2; ++ot) {
        int oc0 = w * 32 + ot * 16 + lg * 4;
        int ch = oc0 >> 3;
        #pragma unroll
        for (int tt = 0; tt < 4; ++tt) {
            int tok = tt * 16 + lr;
            int cz = (ch & 8) | ((ch ^ tok) & 7);
            u32x2 pk = {pack2(vv[ot][tt][0], vv[ot][tt][1]),
                        pack2(vv[ot][tt][2], vv[ot][tt][3])};
            *(u32x2*)(Vt + tok * 128 + cz * 8 + (oc0 & 7)) = pk;
        }
    }
    if (lr == 0) {
        #pragma unroll
        for (int r = 0; r < 4; ++r)
            #pragma unroll
            for (int e = 0; e < 8; ++e)
                red[(w * 4 + lg) * 33 + r * 8 + e] = part[r][e];
    }
    __syncthreads();

    // coalesced V store
    #pragma unroll
    for (int i = 0; i < 4; ++i) {
        int e = tid + i * 256;
        int tok = e >> 4, c = e & 15;
        int cz = (c & 8) | ((c ^ tok) & 7);
        u16x8 val = *(const u16x8*)(Vt + tok * 128 + cz * 8);
        *(u16x8*)(Vbf + (tok0 + tok) * DM + c * 8) = val;
    }
    if (tid < 64) {
        int d = tid >> 3, e = tid & 7;
        int par = d >> 2, r = d & 3;
        float s = 0.f;
        #pragma unroll
        for (int ww = 0; ww < 4; ++ww)
            s += red[(ww * 4 + par) * 33 + r * 8 + e] +
                 red[(ww * 4 + par + 2) * 33 + r * 8 + e];
        scoreacc[(long)blockIdx.x * 64 + tid] = s;
    }
}

// ---------------------------------------------------------------------------
// k_medsoft
// ---------------------------------------------------------------------------
__global__ __launch_bounds__(64)
void k_medsoft(const float* __restrict__ scoreacc, ushort_t* __restrict__ probsb)
{
    __shared__ float sc[64], pl[64];
    const int p = blockIdx.x, tid = threadIdx.x;
    const float* s0 = scoreacc + (long)p * 256;
    sc[tid] = (s0[tid] + s0[64 + tid] + s0[128 + tid] + s0[192 + tid]) * NORMF;
    __syncthreads();
    if (tid < 8) {
        float row[8], st[8];
        #pragma unroll
        for (int e = 0; e < 8; ++e) { row[e] = sc[tid * 8 + e]; st[e] = row[e]; }
        for (int a = 1; a < 8; ++a) {
            float v = st[a]; int b = a - 1;
            while (b >= 0 && st[b] > v) { st[b + 1] = st[b]; --b; }
            st[b + 1] = v;
        }
        float med = st[3];
        float mv[8]; float mx = -3.0e38f;
        #pragma unroll
        for (int e = 0; e < 8; ++e) {
            mv[e] = (row[e] - med > 0.f) ? row[e] : -1e30f;
            mx = fmaxf(mx, mv[e]);
        }
        float z = 0.f, ex[8];
        #pragma unroll
        for (int e = 0; e < 8; ++e) { ex[e] = expf(mv[e] - mx); z += ex[e]; }
        float iz = 1.f / z;
        #pragma unroll
        for (int e = 0; e < 8; ++e) pl[tid * 8 + e] = ex[e] * iz;
    }
    __syncthreads();
    probsb[(long)p * 64 + tid] = f2b(pl[tid]);
}

// ---------------------------------------------------------------------------
// k_tail: fused AO-gather + Wo + LN1(folded) + FFN + LN2 + v.  64 tok2/block.
// (256,3); T14 issue-early vres (held in regs, reused in LN2 epilogue).
// ---------------------------------------------------------------------------
__global__ __launch_bounds__(256, 3)
void k_tail(const ushort_t* __restrict__ Vbf, const ushort_t* __restrict__ Pb,
            const ushort_t* __restrict__ Wot, const float* __restrict__ bo,
            const ushort_t* __restrict__ W1t, const float* __restrict__ G1,
            const float* __restrict__ C1,
            const ushort_t* __restrict__ W2t, const float* __restrict__ b2,
            const float* __restrict__ lng, const float* __restrict__ lnb,
            const float* __restrict__ vres, float* __restrict__ out)
{
    __shared__ __align__(16) char smem[35840];
    ushort_t* Xb  = (ushort_t*)smem;                 // attn tile -> FFN Hid
    ushort_t* Vg  = (ushort_t*)(smem + 16384);       // V gather -> h' (Hp)
    ushort_t* Hp  = (ushort_t*)(smem + 16384);
    float* pS   = (float*)(smem + 32768);            // 1 KB
    float* pQ   = (float*)(smem + 33792);            // 1 KB
    float* mu1S = (float*)(smem + 34816);            // 256 B
    float* rs1S = (float*)(smem + 35072);
    float* mu2S = (float*)(smem + 35328);
    float* rs2S = (float*)(smem + 35584);

    const int tid = threadIdx.x;
    const int w = tid >> 6, l = tid & 63;
    const int lr = l & 15, lg = l >> 4;
    const int wid = ((blockIdx.x & 7) << 8) | (blockIdx.x >> 3);
    const long T0 = (long)wid * 64;
    const int g  = (int)(T0 >> 13);
    const int r0 = (int)((T0 & 8191) >> 5);

    // ---- gather the 64 V rows (issue first: longest-latency scatter) ----
    #pragma unroll
    for (int i = 0; i < 4; ++i) {
        int e = tid + i * 256;
        int ri = e >> 4, c = e & 15;
        int hb = ri >> 5, bm = (ri >> 1) & 15, rr = ri & 1;
        long t = ((long)(g * 32 + hb * 16 + bm)) * 256 + r0 + rr;
        u16x8 val = *(const u16x8*)(Vbf + t * DM + c * 8);
        int cz = (c & 8) | ((c ^ (ri >> 1)) & 7);
        *(u16x8*)(Vg + ri * 128 + cz * 8) = val;
    }
    // ---- T14: issue all vres loads now; latency hides under AO phase ----
    f32x4 xv[4][2];
    #pragma unroll
    for (int tt = 0; tt < 4; ++tt) {
        long gtok = T0 + tt * 16 + lr;
        #pragma unroll
        for (int ot = 0; ot < 2; ++ot)
            xv[tt][ot] = *(const f32x4*)(vres + gtok * DM +
                                         w * 32 + ot * 16 + lg * 4);
    }
    // Wo weight fragments (L2-hot) prefetched pre-barrier too
    bf16x8 aw[2][4];
    #pragma unroll
    for (int ot = 0; ot < 2; ++ot)
        #pragma unroll
        for (int ks = 0; ks < 4; ++ks)
            aw[ot][ks] = *(const bf16x8*)(Wot +
                ((long)((w * 2 + ot) * 4 + ks) * 64 + l) * 8);
    __syncthreads();

    // ---- AO -> Xb (bf16 swz); probs read from global (L1/L2-hot 4KB) ----
    #pragma unroll
    for (int i = 0; i < 4; ++i) {
        int e = tid + i * 256;
        int ti = e >> 4, bm = e & 15;
        int jj = (ti & 31) >> 1, hb = ti & 1, rr = ti >> 5;
        int ri = hb * 32 + bm * 2 + rr;
        int cz = (jj & 8) | ((jj ^ (ri >> 1)) & 7);
        u16x8 v8 = *(const u16x8*)(Vg + ri * 128 + cz * 8);
        float vf[8];
        #pragma unroll
        for (int e2 = 0; e2 < 8; ++e2) vf[e2] = b2f(v8[e2]);
        const ushort_t* pp = Pb + ((long)g * 32 + hb * 16 + bm) * 64;
        float sd[8];
        #pragma unroll
        for (int d = 0; d < 8; ++d) {
            u16x8 pr = *(const u16x8*)(pp + d * 8);
            float s = 0.f;
            #pragma unroll
            for (int e2 = 0; e2 < 8; ++e2) s = fmaf(b2f(pr[e2]), vf[e2], s);
            sd[d] = s;
        }
        u32x4 po = {pack2(sd[0], sd[1]), pack2(sd[2], sd[3]),
                    pack2(sd[4], sd[5]), pack2(sd[6], sd[7])};
        *(u32x4*)(Xb + xb_off(ti, bm)) = po;
    }
    __syncthreads();

    // ---- Wo GEMM (+ residual from reg xv): h' -> Hp (bf16) ----
    float sums[4] = {0, 0, 0, 0}, sqs[4] = {0, 0, 0, 0};
    {
        f32x4 bov[2];
        #pragma unroll
        for (int ot = 0; ot < 2; ++ot)
            bov[ot] = *(const f32x4*)(bo + w * 32 + ot * 16 + lg * 4);

        #pragma unroll
        for (int tt = 0; tt < 4; ++tt) {
            int tok = tt * 16 + lr;
            bf16x8 bfr[4];
            #pragma unroll
            for (int ks = 0; ks < 4; ++ks)
                bfr[ks] = *(const bf16x8*)(Xb + xb_off(tok, ks * 4 + lg));
            f32x4 acc[2] = {(f32x4){0,0,0,0}, (f32x4){0,0,0,0}};
            #pragma unroll
            for (int ks = 0; ks < 4; ++ks) {
                acc[0] = mfma16(aw[0][ks], bfr[ks], acc[0]);
                acc[1] = mfma16(aw[1][ks], bfr[ks], acc[1]);
            }
            #pragma unroll
            for (int ot = 0; ot < 2; ++ot) {
                int oc0 = w * 32 + ot * 16 + lg * 4;
                float hp[4];
                #pragma unroll
                for (int r = 0; r < 4; ++r) {
                    hp[r] = acc[ot][r] + bov[ot][r] + xv[tt][ot][r];
                    sums[tt] += hp[r];
                    sqs[tt] = fmaf(hp[r], hp[r], sqs[tt]);
                }
                int ch = oc0 >> 3;
                int cz = (ch & 8) | ((ch ^ tok) & 7);
                u32x2 pk = {pack2(hp[0], hp[1]), pack2(hp[2], hp[3])};
                *(u32x2*)(Hp + tok * 128 + cz * 8 + (oc0 & 7)) = pk;
            }
        }
    }
    #pragma unroll
    for (int tt = 0; tt < 4; ++tt) {
        sums[tt] += __shfl_xor(sums[tt], 16);
        sums[tt] += __shfl_xor(sums[tt], 32);
        sqs[tt]  += __shfl_xor(sqs[tt], 16);
        sqs[tt]  += __shfl_xor(sqs[tt], 32);
    }
    #pragma unroll
    for (int tt = 0; tt < 4; ++tt)
        if (lg == tt) { pS[(w * 4 + tt) * 16 + lr] = sums[tt];
                        pQ[(w * 4 + tt) * 16 + lr] = sqs[tt]; }
    __syncthreads();
    if (tid < 64) {
        float s = pS[tid] + pS[64 + tid] + pS[128 + tid] + pS[192 + tid];
        float q = pQ[tid] + pQ[64 + tid] + pQ[128 + tid] + pQ[192 + tid];
        float mu = s * 0.0078125f;
        float var = q * 0.0078125f - mu * mu;
        mu1S[tid] = mu;
        rs1S[tid] = rsqrtf(var + 1e-5f);
    }
    __syncthreads();

    // ---- FFN: 4 hidden slices of 128; stage1 reads h' and applies folded LN
    f32x4 oacc[4][2];
    #pragma unroll
    for (int tt = 0; tt < 4; ++tt) {
        oacc[tt][0] = (f32x4){0,0,0,0};
        oacc[tt][1] = (f32x4){0,0,0,0};
    }
    for (int sl = 0; sl < 4; ++sl) {
        // stage 1: tt-outer, bfrag[4] from Hp feeds both hh chains
        {
            bf16x8 a1[2][4];
            f32x4 G1v[2], C1v[2];
            #pragma unroll
            for (int hh = 0; hh < 2; ++hh) {
                #pragma unroll
                for (int ks = 0; ks < 4; ++ks)
                    a1[hh][ks] = *(const bf16x8*)(W1t +
                        ((long)((sl * 8 + w * 2 + hh) * 4 + ks) * 64 + l) * 8);
                int hcb = (sl * 8 + w * 2 + hh) * 16 + lg * 4;
                G1v[hh] = *(const f32x4*)(G1 + hcb);
                C1v[hh] = *(const f32x4*)(C1 + hcb);
            }
            #pragma unroll
            for (int tt = 0; tt < 4; ++tt) {
                int tok = tt * 16 + lr;
                bf16x8 bfr[4];
                #pragma unroll
                for (int ks = 0; ks < 4; ++ks)
                    bfr[ks] = *(const bf16x8*)(Hp + xb_off(tok, ks * 4 + lg));
                f32x4 acc[2] = {(f32x4){0,0,0,0}, (f32x4){0,0,0,0}};
                #pragma unroll
                for (int ks = 0; ks < 4; ++ks) {
                    acc[0] = mfma16(a1[0][ks], bfr[ks], acc[0]);
                    acc[1] = mfma16(a1[1][ks], bfr[ks], acc[1]);
                }
                float mu1 = mu1S[tok], rs1 = rs1S[tok];
                float mneg = -mu1 * rs1;
                #pragma unroll
                for (int hh = 0; hh < 2; ++hh) {
                    float gg[4];
                    #pragma unroll
                    for (int r = 0; r < 4; ++r) {
                        float pre = fmaf(rs1, acc[hh][r],
                                         fmaf(mneg, G1v[hh][r], C1v[hh][r]));
                        gg[r] = gelu_f(pre);
                    }
                    int hc0 = w * 32 + hh * 16 + lg * 4;
                    int ch = hc0 >> 3;
                    int cz = (ch & 8) | ((ch ^ tok) & 7);
                    u32x2 pk = {pack2(gg[0], gg[1]), pack2(gg[2], gg[3])};
                    *(u32x2*)(Xb + tok * 128 + cz * 8 + (hc0 & 7)) = pk;
                }
            }
        }
        __syncthreads();
        // stage 2: tt-outer, bfrag[4] from Xb feeds both op accumulators
        {
            bf16x8 a2[2][4];
            #pragma unroll
            for (int op = 0; op < 2; ++op)
                #pragma unroll
                for (int kl = 0; kl < 4; ++kl)
                    a2[op][kl] = *(const bf16x8*)(W2t +
                        ((long)((w * 2 + op) * 16 + sl * 4 + kl) * 64 + l) * 8);
            #pragma unroll
            for (int tt = 0; tt < 4; ++tt) {
                int tok = tt * 16 + lr;
                bf16x8 bfr[4];
                #pragma unroll
                for (int kl = 0; kl < 4; ++kl)
                    bfr[kl] = *(const bf16x8*)(Xb + xb_off(tok, kl * 4 + lg));
                #pragma unroll
                for (int kl = 0; kl < 4; ++kl) {
                    oacc[tt][0] = mfma16(a2[0][kl], bfr[kl], oacc[tt][0]);
                    oacc[tt][1] = mfma16(a2[1][kl], bfr[kl], oacc[tt][1]);
                }
            }
        }
        __syncthreads();
    }

    // ---- LN2: vvv = oacc + b2 + h, h = LN1-affine(h' from Hp) ----
    #pragma unroll
    for (int tt = 0; tt < 4; ++tt) {
        int tok = tt * 16 + lr;
        float mu1 = mu1S[tok], rs1 = rs1S[tok];
        float s = 0.f, q = 0.f;
        #pragma unroll
        for (int ot = 0; ot < 2; ++ot) {
            int oc0 = w * 32 + ot * 16 + lg * 4;
            f32x4 b2v = *(const f32x4*)(b2 + oc0);
            f32x4 g4 = *(const f32x4*)(lng + oc0);
            f32x4 bb4 = *(const f32x4*)(lnb + oc0);
            int ch = oc0 >> 3;
            int cz = (ch & 8) | ((ch ^ tok) & 7);
            u32x2 hpv = *(const u32x2*)(Hp + tok * 128 + cz * 8 + (oc0 & 7));
            float hr[4] = {b2f_lo(hpv[0]), b2f_hi(hpv[0]),
                           b2f_lo(hpv[1]), b2f_hi(hpv[1])};
            #pragma unroll
            for (int r = 0; r < 4; ++r) {
                float h = (hr[r] - mu1) * rs1 * g4[r] + bb4[r];
                float vvv = oacc[tt][ot][r] + b2v[r] + h;
                s += vvv; q = fmaf(vvv, vvv, q);
            }
        }
        sums[tt] = s; sqs[tt] = q;
    }
    #pragma unroll
    for (int tt = 0; tt < 4; ++tt) {
        sums[tt] += __shfl_xor(sums[tt], 16);
        sums[tt] += __shfl_xor(sums[tt], 32);
        sqs[tt]  += __shfl_xor(sqs[tt], 16);
        sqs[tt]  += __shfl_xor(sqs[tt], 32);
    }
    #pragma unroll
    for (int tt = 0; tt < 4; ++tt)
        if (lg == tt) { pS[(w * 4 + tt) * 16 + lr] = sums[tt];
                        pQ[(w * 4 + tt) * 16 + lr] = sqs[tt]; }
    __syncthreads();
    if (tid < 64) {
        float s = pS[tid] + pS[64 + tid] + pS[128 + tid] + pS[192 + tid];
        float q = pQ[tid] + pQ[64 + tid] + pQ[128 + tid] + pQ[192 + tid];
        float mu = s * 0.0078125f;
        float var = q * 0.0078125f - mu * mu;
        mu2S[tid] = mu;
        rs2S[tid] = rsqrtf(var + 1e-5f);
    }
    __syncthreads();
    #pragma unroll
    for (int tt = 0; tt < 4; ++tt) {
        int tok = tt * 16 + lr;
        long gtok = T0 + tok;
        float mu1 = mu1S[tok], rs1 = rs1S[tok];
        float mu2 = mu2S[tok], rs2 = rs2S[tok];
        #pragma unroll
        for (int ot = 0; ot < 2; ++ot) {
            int oc0 = w * 32 + ot * 16 + lg * 4;
            f32x4 b2v = *(const f32x4*)(b2 + oc0);
            f32x4 g4 = *(const f32x4*)(lng + oc0);
            f32x4 bb4 = *(const f32x4*)(lnb + oc0);
            int ch = oc0 >> 3;
            int cz = (ch & 8) | ((ch ^ tok) & 7);
            u32x2 hpv = *(const u32x2*)(Hp + tok * 128 + cz * 8 + (oc0 & 7));
            float hr[4] = {b2f_lo(hpv[0]), b2f_hi(hpv[0]),
                           b2f_lo(hpv[1]), b2f_hi(hpv[1])};
            f32x4 o;
            #pragma unroll
            for (int r = 0; r < 4; ++r) {
                float h = (hr[r] - mu1) * rs1 * g4[r] + bb4[r];
                float vvv = oacc[tt][ot][r] + b2v[r] + h;
                o[r] = (vvv - mu2) * rs2 * g4[r] + bb4[r] + xv[tt][ot][r];
            }
            *(f32x4*)(out + gtok * DM + oc0) = o;
        }
    }
}

// ---------------------------------------------------------------------------
extern "C" void kernel_launch(void* const* d_in, const int* in_sizes, int n_in,
                              void* d_out, int out_size, void* d_ws, size_t ws_size,
                              hipStream_t stream)
{
    const float* q   = (const float*)d_in[0];
    const float* v   = (const float*)d_in[1];
    const float* Wq  = (const float*)d_in[2];
    const float* bq  = (const float*)d_in[3];
    const float* Wk  = (const float*)d_in[4];
    const float* bk  = (const float*)d_in[5];
    const float* Wv  = (const float*)d_in[6];
    const float* bv  = (const float*)d_in[7];
    const float* Wo  = (const float*)d_in[8];
    const float* bo  = (const float*)d_in[9];
    const float* lng = (const float*)d_in[10];
    const float* lnb = (const float*)d_in[11];
    const float* W1  = (const float*)d_in[12];
    const float* b1  = (const float*)d_in[13];
    const float* W2  = (const float*)d_in[14];
    const float* b2  = (const float*)d_in[15];
    float* out = (float*)d_out;

    char* W = (char*)d_ws;
    ushort_t* Vbf      = (ushort_t*)(W);               // 32 MB
    float*    scoreacc = (float*)(W + 33554432);       // 512 KB
    ushort_t* probsb   = (ushort_t*)(W + 34078720);    // 64 KB (bf16)
    char* wbase = W + 34209792;
    ushort_t* Wqh = (ushort_t*)(wbase);
    ushort_t* Wql = (ushort_t*)(wbase + 32768);
    ushort_t* Wkh = (ushort_t*)(wbase + 65536);
    ushort_t* Wkl = (ushort_t*)(wbase + 98304);
    ushort_t* Wvh = (ushort_t*)(wbase + 131072);
    ushort_t* Wvl = (ushort_t*)(wbase + 163840);
    ushort_t* W1t = (ushort_t*)(wbase + 196608);       // 128 KB
    ushort_t* W2t = (ushort_t*)(wbase + 327680);       // 128 KB
    ushort_t* Wot = (ushort_t*)(wbase + 458752);       // 32 KB
    float*    G1  = (float*)(wbase + 491520);          // 2 KB
    float*    C1  = (float*)(wbase + 493568);          // 2 KB

    dim3 blk(256);
    k_wcvt<<<96, blk, 0, stream>>>(W1, W2, Wo, Wq, Wk, Wv, lng,
                                   W1t, W2t, Wot, Wqh, Wql, Wkh, Wkl, Wvh, Wvl);
    k_lnfold<<<2, blk, 0, stream>>>(W1, lng, lnb, b1, G1, C1);
    k_qkvs<<<2048, blk, 0, stream>>>(q, v, Wqh, Wql, Wkh, Wkl, Wvh,
                                     bq, bk, bv, Vbf, scoreacc);
    k_medsoft<<<512, dim3(64), 0, stream>>>(scoreacc, probsb);
    k_tail<<<2048, blk, 0, stream>>>(Vbf, probsb, Wot, bo, W1t, G1, C1,
                                     W2t, b2, lng, lnb, v, out);
}

// Round 14
// 179.827 us; speedup vs baseline: 1.0937x; 1.0602x over previous
//
#include <hip/hip_runtime.h>
#include <math.h>

// ============================================================================
// Cross-covariance transformer block.  Round 14:
//  - k_tail: exact round-11 config (256,3), no T14 (r13's issue-early vres
//    held 32 regs live across the FFN -> 85MB spill, WRITE 150MB).
//  - k_lnfold MERGED into k_wcvt (blocks 96..103): the standalone 2-block
//    launch was a ~8-10us serialization bubble on a 256-CU chip (the r8+
//    "rest of pipeline" regression 72->79us).  Grid 96 -> 104.
// ============================================================================

typedef __bf16 bf16x8 __attribute__((ext_vector_type(8)));
typedef float f32x4 __attribute__((ext_vector_type(4)));
typedef unsigned short u16x8 __attribute__((ext_vector_type(8)));
typedef unsigned int u32x2 __attribute__((ext_vector_type(2)));
typedef unsigned int u32x4 __attribute__((ext_vector_type(4)));
typedef unsigned short ushort_t;

static constexpr int  DM   = 128;
static constexpr long NTOK = 131072;                 // B*S = 32*4096
static constexpr float NORMF = 0.17677669529663687f; // 1/sqrt(32)

__device__ __forceinline__ unsigned short f2b(float x) {
    __bf16 b = (__bf16)x;
    return __builtin_bit_cast(unsigned short, b);
}
__device__ __forceinline__ float b2f(unsigned short h) {
    return __builtin_bit_cast(float, ((unsigned)h) << 16);
}
__device__ __forceinline__ float b2f_lo(unsigned u) {
    return __builtin_bit_cast(float, u << 16);
}
__device__ __forceinline__ float b2f_hi(unsigned u) {
    return __builtin_bit_cast(float, u & 0xffff0000u);
}
__device__ __forceinline__ unsigned pack2(float a, float b) {
    return (unsigned)f2b(a) | ((unsigned)f2b(b) << 16);
}
__device__ __forceinline__ f32x4 mfma16(bf16x8 a, bf16x8 b, f32x4 c) {
    return __builtin_amdgcn_mfma_f32_16x16x32_bf16(a, b, c, 0, 0, 0);
}
// [64][128] bf16 tile, 16B chunks XOR-swizzled by tok&7
__device__ __forceinline__ int xb_off(int tok, int chunk) {
    int c = (chunk & 8) | ((chunk ^ tok) & 7);
    return tok * 128 + c * 8;
}
// tanh-form gelu
__device__ __forceinline__ float gelu_f(float x) {
    float x2 = x * x;
    float y = -x * fmaf(0.0713548162f, x2, 1.5957691216f);
    float e = __expf(y);
    return x * __builtin_amdgcn_rcpf(1.0f + e);
}

// ---------------------------------------------------------------------------
// k_wcvt: weights -> MFMA-A-fragment-linear bf16 (W1t ln_g-folded), PLUS
// blocks 96..103 compute G1[j]=sum lng*W1, C1[j]=sum lnb*W1 + b1 (parallel
// k-split, coalesced j-reads) -- replaces the serialization-bubble k_lnfold.
// ---------------------------------------------------------------------------
__global__ __launch_bounds__(256)
void k_wcvt(const float* __restrict__ W1, const float* __restrict__ W2,
            const float* __restrict__ Wo, const float* __restrict__ Wq,
            const float* __restrict__ Wk, const float* __restrict__ Wv,
            const float* __restrict__ lng, const float* __restrict__ lnb,
            const float* __restrict__ b1,
            ushort_t* __restrict__ W1t, ushort_t* __restrict__ W2t,
            ushort_t* __restrict__ Wot,
            ushort_t* __restrict__ Wqh, ushort_t* __restrict__ Wql,
            ushort_t* __restrict__ Wkh, ushort_t* __restrict__ Wkl,
            ushort_t* __restrict__ Wvh, ushort_t* __restrict__ Wvl,
            float* __restrict__ G1, float* __restrict__ C1)
{
    if (blockIdx.x >= 96) {                 // ---- lnfold blocks ----
        __shared__ float gpart[4][64], bpart[4][64];
        int kp = threadIdx.x >> 6;          // 0..3
        int jl = threadIdx.x & 63;
        int j  = (blockIdx.x - 96) * 64 + jl;
        float gs = 0.f, bs = 0.f;
        #pragma unroll 8
        for (int kk = 0; kk < 32; ++kk) {
            int k = kp * 32 + kk;
            float wv = W1[(long)k * 512 + j];
            gs = fmaf(lng[k], wv, gs);
            bs = fmaf(lnb[k], wv, bs);
        }
        gpart[kp][jl] = gs;
        bpart[kp][jl] = bs;
        __syncthreads();
        if (kp == 0) {
            float g = gpart[0][jl] + gpart[1][jl] + gpart[2][jl] + gpart[3][jl];
            float b = bpart[0][jl] + bpart[1][jl] + bpart[2][jl] + bpart[3][jl];
            G1[j] = g;
            C1[j] = b + b1[j];
        }
        return;
    }
    int frag = blockIdx.x * 4 + (threadIdx.x >> 6);
    int l = threadIdx.x & 63;
    int lr = l & 15, lg = l >> 4;
    u16x8 v;
    if (frag < 128) {                       // W1t (g-folded): 32 ht x 4 ks
        int ht = frag >> 2, ks = frag & 3;
        #pragma unroll
        for (int j = 0; j < 8; ++j) {
            int k = ks * 32 + lg * 8 + j;
            v[j] = f2b(lng[k] * W1[(long)k * 512 + ht * 16 + lr]);
        }
        *(u16x8*)(W1t + ((long)frag * 64 + l) * 8) = v;
    } else if (frag < 256) {                // W2t: 8 oc-tiles x 16 k-steps
        int f = frag - 128;
        int ot = f >> 4, ks = f & 15;
        #pragma unroll
        for (int j = 0; j < 8; ++j)
            v[j] = f2b(W2[(ks * 32 + lg * 8 + j) * 128 + ot * 16 + lr]);
        *(u16x8*)(W2t + ((long)f * 64 + l) * 8) = v;
    } else if (frag < 288) {                // Wot: 8 oc-tiles x 4 k-steps
        int f = frag - 256;
        int ot = f >> 2, ks = f & 3;
        #pragma unroll
        for (int j = 0; j < 8; ++j)
            v[j] = f2b(Wo[(ks * 32 + lg * 8 + j) * 128 + ot * 16 + lr]);
        *(u16x8*)(Wot + ((long)f * 64 + l) * 8) = v;
    } else {                                // Wq/Wk/Wv hi+lo, 32 frags each
        int f = frag - 288;
        const float* S = (f < 32) ? Wq : (f < 64) ? Wk : Wv;
        ushort_t* dh = (f < 32) ? Wqh : (f < 64) ? Wkh : Wvh;
        ushort_t* dl = (f < 32) ? Wql : (f < 64) ? Wkl : Wvl;
        int fl = f & 31, ot = fl >> 2, ks = fl & 3;
        u16x8 vh, vl;
        #pragma unroll
        for (int j = 0; j < 8; ++j) {
            float x = S[(ks * 32 + lg * 8 + j) * 128 + ot * 16 + lr];
            __bf16 bh = (__bf16)x;
            vh[j] = __builtin_bit_cast(unsigned short, bh);
            vl[j] = f2b(x - (float)bh);
        }
        *(u16x8*)(dh + ((long)fl * 64 + l) * 8) = vh;
        *(u16x8*)(dl + ((long)fl * 64 + l) * 8) = vl;
    }
}

// ---------------------------------------------------------------------------
// k_qkvs: 64 tokens/block.  Split-bf16 MFMA for Q (3-pass, from v), K
// (3-pass), V (1-pass, from q); 8-group normalize Q,K; partial scores.
// ---------------------------------------------------------------------------
__global__ __launch_bounds__(256, 2)
void k_qkvs(const float* __restrict__ qin, const float* __restrict__ vin,
            const ushort_t* __restrict__ Wqh, const ushort_t* __restrict__ Wql,
            const ushort_t* __restrict__ Wkh, const ushort_t* __restrict__ Wkl,
            const ushort_t* __restrict__ Wvh,
            const float* __restrict__ bq, const float* __restrict__ bk,
            const float* __restrict__ bv,
            ushort_t* __restrict__ Vbf, float* __restrict__ scoreacc)
{
    __shared__ __align__(16) char smem[65536];
    ushort_t* vhi = (ushort_t*)smem;            // [64][128] swz  (input v)
    ushort_t* vlo = vhi + 8192;
    ushort_t* qhi = vlo + 8192;                 // (input q)
    ushort_t* qlo = qhi + 8192;
    ushort_t* Vt  = (ushort_t*)smem;            // alias (16 KB) after phases
    float*    red = (float*)(smem + 16384);     // [16][33] alias

    const int tid = threadIdx.x;
    const int w = tid >> 6, l = tid & 63;
    const int lr = l & 15, lg = l >> 4;
    const long tok0 = (long)blockIdx.x * 64;

    // ---- stage inputs, split hi/lo ----
    #pragma unroll
    for (int i = 0; i < 4; ++i) {
        int e = tid + i * 256;
        int tok = e >> 4, c = e & 15;
        long base = (tok0 + tok) * DM + c * 8;
        int xo = xb_off(tok, c);
        {
            float4 a0 = *(const float4*)(vin + base);
            float4 a1 = *(const float4*)(vin + base + 4);
            float xs[8] = {a0.x, a0.y, a0.z, a0.w, a1.x, a1.y, a1.z, a1.w};
            u16x8 hi, lo;
            #pragma unroll
            for (int jj = 0; jj < 8; ++jj) {
                __bf16 bh = (__bf16)xs[jj];
                hi[jj] = __builtin_bit_cast(unsigned short, bh);
                lo[jj] = f2b(xs[jj] - (float)bh);
            }
            *(u16x8*)(vhi + xo) = hi;
            *(u16x8*)(vlo + xo) = lo;
        }
        {
            float4 a0 = *(const float4*)(qin + base);
            float4 a1 = *(const float4*)(qin + base + 4);
            float xs[8] = {a0.x, a0.y, a0.z, a0.w, a1.x, a1.y, a1.z, a1.w};
            u16x8 hi, lo;
            #pragma unroll
            for (int jj = 0; jj < 8; ++jj) {
                __bf16 bh = (__bf16)xs[jj];
                hi[jj] = __builtin_bit_cast(unsigned short, bh);
                lo[jj] = f2b(xs[jj] - (float)bh);
            }
            *(u16x8*)(qhi + xo) = hi;
            *(u16x8*)(qlo + xo) = lo;
        }
    }
    __syncthreads();

    // ---- Q phase (input v) ----
    float qv[2][4][4];
    {
        f32x4 acc[2][4];
        #pragma unroll
        for (int ot = 0; ot < 2; ++ot)
            #pragma unroll
            for (int tt = 0; tt < 4; ++tt) acc[ot][tt] = (f32x4){0,0,0,0};
        #pragma unroll
        for (int ks = 0; ks < 4; ++ks) {
            bf16x8 wh[2], wl[2];
            #pragma unroll
            for (int ot = 0; ot < 2; ++ot) {
                int fi = (((w * 2 + ot) * 4 + ks) * 64 + l) * 8;
                wh[ot] = *(const bf16x8*)(Wqh + fi);
                wl[ot] = *(const bf16x8*)(Wql + fi);
            }
            #pragma unroll
            for (int tt = 0; tt < 4; ++tt) {
                int xo = xb_off(tt * 16 + lr, ks * 4 + lg);
                bf16x8 xh = *(const bf16x8*)(vhi + xo);
                bf16x8 xl = *(const bf16x8*)(vlo + xo);
                #pragma unroll
                for (int ot = 0; ot < 2; ++ot) {
                    acc[ot][tt] = mfma16(wh[ot], xh, acc[ot][tt]);
                    acc[ot][tt] = mfma16(wh[ot], xl, acc[ot][tt]);
                    acc[ot][tt] = mfma16(wl[ot], xh, acc[ot][tt]);
                }
            }
        }
        #pragma unroll
        for (int ot = 0; ot < 2; ++ot) {
            f32x4 bqv = *(const f32x4*)(bq + w * 32 + ot * 16 + lg * 4);
            #pragma unroll
            for (int tt = 0; tt < 4; ++tt) {
                float s2 = 0.f;
                #pragma unroll
                for (int r = 0; r < 4; ++r) {
                    float x = acc[ot][tt][r] + bqv[r];
                    qv[ot][tt][r] = x;
                    s2 = fmaf(x, x, s2);
                }
                s2 += __shfl_xor(s2, 16);
                float inv = 1.0f / fmaxf(sqrtf(s2), 1e-12f);
                #pragma unroll
                for (int r = 0; r < 4; ++r) qv[ot][tt][r] *= inv;
            }
        }
    }

    // ---- K (3-pass) + V (1-pass) + incremental score accumulation ----
    float vv[2][4][4];
    float part[4][8];
    #pragma unroll
    for (int r = 0; r < 4; ++r)
        #pragma unroll
        for (int e = 0; e < 8; ++e) part[r][e] = 0.f;
    {
        f32x4 acck[2][4], accv[2][4];
        #pragma unroll
        for (int ot = 0; ot < 2; ++ot)
            #pragma unroll
            for (int tt = 0; tt < 4; ++tt) {
                acck[ot][tt] = (f32x4){0,0,0,0};
                accv[ot][tt] = (f32x4){0,0,0,0};
            }
        #pragma unroll
        for (int ks = 0; ks < 4; ++ks) {
            bf16x8 whk[2], wlk[2], whv[2];
            #pragma unroll
            for (int ot = 0; ot < 2; ++ot) {
                int fi = (((w * 2 + ot) * 4 + ks) * 64 + l) * 8;
                whk[ot] = *(const bf16x8*)(Wkh + fi);
                wlk[ot] = *(const bf16x8*)(Wkl + fi);
                whv[ot] = *(const bf16x8*)(Wvh + fi);
            }
            #pragma unroll
            for (int tt = 0; tt < 4; ++tt) {
                int xo = xb_off(tt * 16 + lr, ks * 4 + lg);
                bf16x8 xh = *(const bf16x8*)(qhi + xo);
                bf16x8 xl = *(const bf16x8*)(qlo + xo);
                #pragma unroll
                for (int ot = 0; ot < 2; ++ot) {
                    acck[ot][tt] = mfma16(whk[ot], xh, acck[ot][tt]);
                    acck[ot][tt] = mfma16(whk[ot], xl, acck[ot][tt]);
                    acck[ot][tt] = mfma16(wlk[ot], xh, acck[ot][tt]);
                    accv[ot][tt] = mfma16(whv[ot], xh, accv[ot][tt]);
                }
            }
        }
        const int h0 = (lg & 1) * 4;
        #pragma unroll
        for (int ot = 0; ot < 2; ++ot) {
            f32x4 bkv = *(const f32x4*)(bk + w * 32 + ot * 16 + lg * 4);
            f32x4 bvv = *(const f32x4*)(bv + w * 32 + ot * 16 + lg * 4);
            #pragma unroll
            for (int tt = 0; tt < 4; ++tt) {
                float kq[4];
                float s2 = 0.f;
                #pragma unroll
                for (int r = 0; r < 4; ++r) {
                    float x = acck[ot][tt][r] + bkv[r];
                    kq[r] = x;
                    s2 = fmaf(x, x, s2);
                    vv[ot][tt][r] = accv[ot][tt][r] + bvv[r];
                }
                s2 += __shfl_xor(s2, 16);
                float inv = 1.0f / fmaxf(sqrtf(s2), 1e-12f);
                #pragma unroll
                for (int r = 0; r < 4; ++r) kq[r] *= inv;
                float ko[4];
                #pragma unroll
                for (int r = 0; r < 4; ++r) ko[r] = __shfl_xor(kq[r], 16);
                float ke[8];
                #pragma unroll
                for (int r = 0; r < 4; ++r) {
                    ke[h0 + r] = kq[r];
                    ke[(h0 ^ 4) + r] = ko[r];
                }
                #pragma unroll
                for (int r = 0; r < 4; ++r)
                    #pragma unroll
                    for (int e = 0; e < 8; ++e)
                        part[r][e] = fmaf(qv[ot][tt][r], ke[e], part[r][e]);
            }
        }
    }
    // reduce partials over lr lanes (bits 0..3)
    #pragma unroll
    for (int r = 0; r < 4; ++r)
        #pragma unroll
        for (int e = 0; e < 8; ++e) {
            float p = part[r][e];
            p += __shfl_xor(p, 1);
            p += __shfl_xor(p, 2);
            p += __shfl_xor(p, 4);
            p += __shfl_xor(p, 8);
            part[r][e] = p;
        }
    __syncthreads();   // x-tiles fully consumed; alias regions now writable

    // V regs -> Vt (swizzled bf16 [64][128])
    #pragma unroll
    for (int ot = 0; ot < 2; ++ot) {
        int oc0 = w * 32 + ot * 16 + lg * 4;
        int ch = oc0 >> 3;
        #pragma unroll
        for (int tt = 0; tt < 4; ++tt) {
            int tok = tt * 16 + lr;
            int cz = (ch & 8) | ((ch ^ tok) & 7);
            u32x2 pk = {pack2(vv[ot][tt][0], vv[ot][tt][1]),
                        pack2(vv[ot][tt][2], vv[ot][tt][3])};
            *(u32x2*)(Vt + tok * 128 + cz * 8 + (oc0 & 7)) = pk;
        }
    }
    if (lr == 0) {
        #pragma unroll
        for (int r = 0; r < 4; ++r)
            #pragma unroll
            for (int e = 0; e < 8; ++e)
                red[(w * 4 + lg) * 33 + r * 8 + e] = part[r][e];
    }
    __syncthreads();

    // coalesced V store
    #pragma unroll
    for (int i = 0; i < 4; ++i) {
        int e = tid + i * 256;
        int tok = e >> 4, c = e & 15;
        int cz = (c & 8) | ((c ^ tok) & 7);
        u16x8 val = *(const u16x8*)(Vt + tok * 128 + cz * 8);
        *(u16x8*)(Vbf + (tok0 + tok) * DM + c * 8) = val;
    }
    if (tid < 64) {
        int d = tid >> 3, e = tid & 7;
        int par = d >> 2, r = d & 3;
        float s = 0.f;
        #pragma unroll
        for (int ww = 0; ww < 4; ++ww)
            s += red[(ww * 4 + par) * 33 + r * 8 + e] +
                 red[(ww * 4 + par + 2) * 33 + r * 8 + e];
        scoreacc[(long)blockIdx.x * 64 + tid] = s;
    }
}

// ---------------------------------------------------------------------------
// k_medsoft
// ---------------------------------------------------------------------------
__global__ __launch_bounds__(64)
void k_medsoft(const float* __restrict__ scoreacc, ushort_t* __restrict__ probsb)
{
    __shared__ float sc[64], pl[64];
    const int p = blockIdx.x, tid = threadIdx.x;
    const float* s0 = scoreacc + (long)p * 256;
    sc[tid] = (s0[tid] + s0[64 + tid] + s0[128 + tid] + s0[192 + tid]) * NORMF;
    __syncthreads();
    if (tid < 8) {
        float row[8], st[8];
        #pragma unroll
        for (int e = 0; e < 8; ++e) { row[e] = sc[tid * 8 + e]; st[e] = row[e]; }
        for (int a = 1; a < 8; ++a) {
            float v = st[a]; int b = a - 1;
            while (b >= 0 && st[b] > v) { st[b + 1] = st[b]; --b; }
            st[b + 1] = v;
        }
        float med = st[3];
        float mv[8]; float mx = -3.0e38f;
        #pragma unroll
        for (int e = 0; e < 8; ++e) {
            mv[e] = (row[e] - med > 0.f) ? row[e] : -1e30f;
            mx = fmaxf(mx, mv[e]);
        }
        float z = 0.f, ex[8];
        #pragma unroll
        for (int e = 0; e < 8; ++e) { ex[e] = expf(mv[e] - mx); z += ex[e]; }
        float iz = 1.f / z;
        #pragma unroll
        for (int e = 0; e < 8; ++e) pl[tid * 8 + e] = ex[e] * iz;
    }
    __syncthreads();
    probsb[(long)p * 64 + tid] = f2b(pl[tid]);
}

// ---------------------------------------------------------------------------
// k_tail: fused AO-gather + Wo + LN1(folded) + FFN + LN2 + v.  64 tok2/block.
// Exact round-11 configuration: (256,3), hoisted B-fragment reads, no T14.
// ---------------------------------------------------------------------------
__global__ __launch_bounds__(256, 3)
void k_tail(const ushort_t* __restrict__ Vbf, const ushort_t* __restrict__ Pb,
            const ushort_t* __restrict__ Wot, const float* __restrict__ bo,
            const ushort_t* __restrict__ W1t, const float* __restrict__ G1,
            const float* __restrict__ C1,
            const ushort_t* __restrict__ W2t, const float* __restrict__ b2,
            const float* __restrict__ lng, const float* __restrict__ lnb,
            const float* __restrict__ vres, float* __restrict__ out)
{
    __shared__ __align__(16) char smem[35840];
    ushort_t* Xb  = (ushort_t*)smem;                 // attn tile -> FFN Hid
    ushort_t* Vg  = (ushort_t*)(smem + 16384);       // V gather -> h' (Hp)
    ushort_t* Hp  = (ushort_t*)(smem + 16384);
    float* pS   = (float*)(smem + 32768);            // 1 KB
    float* pQ   = (float*)(smem + 33792);            // 1 KB
    float* mu1S = (float*)(smem + 34816);            // 256 B
    float* rs1S = (float*)(smem + 35072);
    float* mu2S = (float*)(smem + 35328);
    float* rs2S = (float*)(smem + 35584);

    const int tid = threadIdx.x;
    const int w = tid >> 6, l = tid & 63;
    const int lr = l & 15, lg = l >> 4;
    const int wid = ((blockIdx.x & 7) << 8) | (blockIdx.x >> 3);
    const long T0 = (long)wid * 64;
    const int g  = (int)(T0 >> 13);
    const int r0 = (int)((T0 & 8191) >> 5);

    // ---- gather the 64 V rows ----
    #pragma unroll
    for (int i = 0; i < 4; ++i) {
        int e = tid + i * 256;
        int ri = e >> 4, c = e & 15;
        int hb = ri >> 5, bm = (ri >> 1) & 15, rr = ri & 1;
        long t = ((long)(g * 32 + hb * 16 + bm)) * 256 + r0 + rr;
        u16x8 val = *(const u16x8*)(Vbf + t * DM + c * 8);
        int cz = (c & 8) | ((c ^ (ri >> 1)) & 7);
        *(u16x8*)(Vg + ri * 128 + cz * 8) = val;
    }
    __syncthreads();

    // ---- AO -> Xb (bf16 swz); probs read from global (L1/L2-hot 4KB) ----
    #pragma unroll
    for (int i = 0; i < 4; ++i) {
        int e = tid + i * 256;
        int ti = e >> 4, bm = e & 15;
        int jj = (ti & 31) >> 1, hb = ti & 1, rr = ti >> 5;
        int ri = hb * 32 + bm * 2 + rr;
        int cz = (jj & 8) | ((jj ^ (ri >> 1)) & 7);
        u16x8 v8 = *(const u16x8*)(Vg + ri * 128 + cz * 8);
        float vf[8];
        #pragma unroll
        for (int e2 = 0; e2 < 8; ++e2) vf[e2] = b2f(v8[e2]);
        const ushort_t* pp = Pb + ((long)g * 32 + hb * 16 + bm) * 64;
        float sd[8];
        #pragma unroll
        for (int d = 0; d < 8; ++d) {
            u16x8 pr = *(const u16x8*)(pp + d * 8);
            float s = 0.f;
            #pragma unroll
            for (int e2 = 0; e2 < 8; ++e2) s = fmaf(b2f(pr[e2]), vf[e2], s);
            sd[d] = s;
        }
        u32x4 po = {pack2(sd[0], sd[1]), pack2(sd[2], sd[3]),
                    pack2(sd[4], sd[5]), pack2(sd[6], sd[7])};
        *(u32x4*)(Xb + xb_off(ti, bm)) = po;
    }
    __syncthreads();

    // ---- Wo GEMM (+ residual): h' -> Hp (bf16), stats in regs.
    //      tt-outer: bfrag[4] read once, feeds both ot chains. ----
    float sums[4] = {0, 0, 0, 0}, sqs[4] = {0, 0, 0, 0};
    {
        bf16x8 aw[2][4];
        #pragma unroll
        for (int ot = 0; ot < 2; ++ot)
            #pragma unroll
            for (int ks = 0; ks < 4; ++ks)
                aw[ot][ks] = *(const bf16x8*)(Wot +
                    ((long)((w * 2 + ot) * 4 + ks) * 64 + l) * 8);
        f32x4 bov[2];
        #pragma unroll
        for (int ot = 0; ot < 2; ++ot)
            bov[ot] = *(const f32x4*)(bo + w * 32 + ot * 16 + lg * 4);

        #pragma unroll
        for (int tt = 0; tt < 4; ++tt) {
            int tok = tt * 16 + lr;
            bf16x8 bfr[4];
            #pragma unroll
            for (int ks = 0; ks < 4; ++ks)
                bfr[ks] = *(const bf16x8*)(Xb + xb_off(tok, ks * 4 + lg));
            f32x4 acc[2] = {(f32x4){0,0,0,0}, (f32x4){0,0,0,0}};
            #pragma unroll
            for (int ks = 0; ks < 4; ++ks) {
                acc[0] = mfma16(aw[0][ks], bfr[ks], acc[0]);
                acc[1] = mfma16(aw[1][ks], bfr[ks], acc[1]);
            }
            long gtok = T0 + tok;
            #pragma unroll
            for (int ot = 0; ot < 2; ++ot) {
                int oc0 = w * 32 + ot * 16 + lg * 4;
                f32x4 xv = *(const f32x4*)(vres + gtok * DM + oc0);
                float hp[4];
                #pragma unroll
                for (int r = 0; r < 4; ++r) {
                    hp[r] = acc[ot][r] + bov[ot][r] + xv[r];
                    sums[tt] += hp[r];
                    sqs[tt] = fmaf(hp[r], hp[r], sqs[tt]);
                }
                int ch = oc0 >> 3;
                int cz = (ch & 8) | ((ch ^ tok) & 7);
                u32x2 pk = {pack2(hp[0], hp[1]), pack2(hp[2], hp[3])};
                *(u32x2*)(Hp + tok * 128 + cz * 8 + (oc0 & 7)) = pk;
            }
        }
    }
    #pragma unroll
    for (int tt = 0; tt < 4; ++tt) {
        sums[tt] += __shfl_xor(sums[tt], 16);
        sums[tt] += __shfl_xor(sums[tt], 32);
        sqs[tt]  += __shfl_xor(sqs[tt], 16);
        sqs[tt]  += __shfl_xor(sqs[tt], 32);
    }
    #pragma unroll
    for (int tt = 0; tt < 4; ++tt)
        if (lg == tt) { pS[(w * 4 + tt) * 16 + lr] = sums[tt];
                        pQ[(w * 4 + tt) * 16 + lr] = sqs[tt]; }
    __syncthreads();
    if (tid < 64) {
        float s = pS[tid] + pS[64 + tid] + pS[128 + tid] + pS[192 + tid];
        float q = pQ[tid] + pQ[64 + tid] + pQ[128 + tid] + pQ[192 + tid];
        float mu = s * 0.0078125f;
        float var = q * 0.0078125f - mu * mu;
        mu1S[tid] = mu;
        rs1S[tid] = rsqrtf(var + 1e-5f);
    }
    __syncthreads();

    // ---- FFN: 4 hidden slices of 128; stage1 reads h' and applies folded LN
    f32x4 oacc[4][2];
    #pragma unroll
    for (int tt = 0; tt < 4; ++tt) {
        oacc[tt][0] = (f32x4){0,0,0,0};
        oacc[tt][1] = (f32x4){0,0,0,0};
    }
    for (int sl = 0; sl < 4; ++sl) {
        // stage 1: tt-outer, bfrag[4] from Hp feeds both hh chains
        {
            bf16x8 a1[2][4];
            f32x4 G1v[2], C1v[2];
            #pragma unroll
            for (int hh = 0; hh < 2; ++hh) {
                #pragma unroll
                for (int ks = 0; ks < 4; ++ks)
                    a1[hh][ks] = *(const bf16x8*)(W1t +
                        ((long)((sl * 8 + w * 2 + hh) * 4 + ks) * 64 + l) * 8);
                int hcb = (sl * 8 + w * 2 + hh) * 16 + lg * 4;
                G1v[hh] = *(const f32x4*)(G1 + hcb);
                C1v[hh] = *(const f32x4*)(C1 + hcb);
            }
            #pragma unroll
            for (int tt = 0; tt < 4; ++tt) {
                int tok = tt * 16 + lr;
                bf16x8 bfr[4];
                #pragma unroll
                for (int ks = 0; ks < 4; ++ks)
                    bfr[ks] = *(const bf16x8*)(Hp + xb_off(tok, ks * 4 + lg));
                f32x4 acc[2] = {(f32x4){0,0,0,0}, (f32x4){0,0,0,0}};
                #pragma unroll
                for (int ks = 0; ks < 4; ++ks) {
                    acc[0] = mfma16(a1[0][ks], bfr[ks], acc[0]);
                    acc[1] = mfma16(a1[1][ks], bfr[ks], acc[1]);
                }
                float mu1 = mu1S[tok], rs1 = rs1S[tok];
                float mneg = -mu1 * rs1;
                #pragma unroll
                for (int hh = 0; hh < 2; ++hh) {
                    float gg[4];
                    #pragma unroll
                    for (int r = 0; r < 4; ++r) {
                        float pre = fmaf(rs1, acc[hh][r],
                                         fmaf(mneg, G1v[hh][r], C1v[hh][r]));
                        gg[r] = gelu_f(pre);
                    }
                    int hc0 = w * 32 + hh * 16 + lg * 4;
                    int ch = hc0 >> 3;
                    int cz = (ch & 8) | ((ch ^ tok) & 7);
                    u32x2 pk = {pack2(gg[0], gg[1]), pack2(gg[2], gg[3])};
                    *(u32x2*)(Xb + tok * 128 + cz * 8 + (hc0 & 7)) = pk;
                }
            }
        }
        __syncthreads();
        // stage 2: tt-outer, bfrag[4] from Xb feeds both op accumulators
        {
            bf16x8 a2[2][4];
            #pragma unroll
            for (int op = 0; op < 2; ++op)
                #pragma unroll
                for (int kl = 0; kl < 4; ++kl)
                    a2[op][kl] = *(const bf16x8*)(W2t +
                        ((long)((w * 2 + op) * 16 + sl * 4 + kl) * 64 + l) * 8);
            #pragma unroll
            for (int tt = 0; tt < 4; ++tt) {
                int tok = tt * 16 + lr;
                bf16x8 bfr[4];
                #pragma unroll
                for (int kl = 0; kl < 4; ++kl)
                    bfr[kl] = *(const bf16x8*)(Xb + xb_off(tok, kl * 4 + lg));
                #pragma unroll
                for (int kl = 0; kl < 4; ++kl) {
                    oacc[tt][0] = mfma16(a2[0][kl], bfr[kl], oacc[tt][0]);
                    oacc[tt][1] = mfma16(a2[1][kl], bfr[kl], oacc[tt][1]);
                }
            }
        }
        __syncthreads();
    }

    // ---- LN2: vvv = oacc + b2 + h, h = LN1-affine(h' from Hp) ----
    #pragma unroll
    for (int tt = 0; tt < 4; ++tt) {
        int tok = tt * 16 + lr;
        float mu1 = mu1S[tok], rs1 = rs1S[tok];
        float s = 0.f, q = 0.f;
        #pragma unroll
        for (int ot = 0; ot < 2; ++ot) {
            int oc0 = w * 32 + ot * 16 + lg * 4;
            f32x4 b2v = *(const f32x4*)(b2 + oc0);
            f32x4 g4 = *(const f32x4*)(lng + oc0);
            f32x4 bb4 = *(const f32x4*)(lnb + oc0);
            int ch = oc0 >> 3;
            int cz = (ch & 8) | ((ch ^ tok) & 7);
            u32x2 hpv = *(const u32x2*)(Hp + tok * 128 + cz * 8 + (oc0 & 7));
            float hr[4] = {b2f_lo(hpv[0]), b2f_hi(hpv[0]),
                           b2f_lo(hpv[1]), b2f_hi(hpv[1])};
            #pragma unroll
            for (int r = 0; r < 4; ++r) {
                float h = (hr[r] - mu1) * rs1 * g4[r] + bb4[r];
                float vvv = oacc[tt][ot][r] + b2v[r] + h;
                s += vvv; q = fmaf(vvv, vvv, q);
            }
        }
        sums[tt] = s; sqs[tt] = q;
    }
    #pragma unroll
    for (int tt = 0; tt < 4; ++tt) {
        sums[tt] += __shfl_xor(sums[tt], 16);
        sums[tt] += __shfl_xor(sums[tt], 32);
        sqs[tt]  += __shfl_xor(sqs[tt], 16);
        sqs[tt]  += __shfl_xor(sqs[tt], 32);
    }
    #pragma unroll
    for (int tt = 0; tt < 4; ++tt)
        if (lg == tt) { pS[(w * 4 + tt) * 16 + lr] = sums[tt];
                        pQ[(w * 4 + tt) * 16 + lr] = sqs[tt]; }
    __syncthreads();
    if (tid < 64) {
        float s = pS[tid] + pS[64 + tid] + pS[128 + tid] + pS[192 + tid];
        float q = pQ[tid] + pQ[64 + tid] + pQ[128 + tid] + pQ[192 + tid];
        float mu = s * 0.0078125f;
        float var = q * 0.0078125f - mu * mu;
        mu2S[tid] = mu;
        rs2S[tid] = rsqrtf(var + 1e-5f);
    }
    __syncthreads();
    #pragma unroll
    for (int tt = 0; tt < 4; ++tt) {
        int tok = tt * 16 + lr;
        long gtok = T0 + tok;
        float mu1 = mu1S[tok], rs1 = rs1S[tok];
        float mu2 = mu2S[tok], rs2 = rs2S[tok];
        #pragma unroll
        for (int ot = 0; ot < 2; ++ot) {
            int oc0 = w * 32 + ot * 16 + lg * 4;
            f32x4 b2v = *(const f32x4*)(b2 + oc0);
            f32x4 g4 = *(const f32x4*)(lng + oc0);
            f32x4 bb4 = *(const f32x4*)(lnb + oc0);
            int ch = oc0 >> 3;
            int cz = (ch & 8) | ((ch ^ tok) & 7);
            u32x2 hpv = *(const u32x2*)(Hp + tok * 128 + cz * 8 + (oc0 & 7));
            float hr[4] = {b2f_lo(hpv[0]), b2f_hi(hpv[0]),
                           b2f_lo(hpv[1]), b2f_hi(hpv[1])};
            f32x4 vv4 = *(const f32x4*)(vres + gtok * DM + oc0);
            f32x4 o;
            #pragma unroll
            for (int r = 0; r < 4; ++r) {
                float h = (hr[r] - mu1) * rs1 * g4[r] + bb4[r];
                float vvv = oacc[tt][ot][r] + b2v[r] + h;
                o[r] = (vvv - mu2) * rs2 * g4[r] + bb4[r] + vv4[r];
            }
            *(f32x4*)(out + gtok * DM + oc0) = o;
        }
    }
}

// ---------------------------------------------------------------------------
extern "C" void kernel_launch(void* const* d_in, const int* in_sizes, int n_in,
                              void* d_out, int out_size, void* d_ws, size_t ws_size,
                              hipStream_t stream)
{
    const float* q   = (const float*)d_in[0];
    const float* v   = (const float*)d_in[1];
    const float* Wq  = (const float*)d_in[2];
    const float* bq  = (const float*)d_in[3];
    const float* Wk  = (const float*)d_in[4];
    const float* bk  = (const float*)d_in[5];
    const float* Wv  = (const float*)d_in[6];
    const float* bv  = (const float*)d_in[7];
    const float* Wo  = (const float*)d_in[8];
    const float* bo  = (const float*)d_in[9];
    const float* lng = (const float*)d_in[10];
    const float* lnb = (const float*)d_in[11];
    const float* W1  = (const float*)d_in[12];
    const float* b1  = (const float*)d_in[13];
    const float* W2  = (const float*)d_in[14];
    const float* b2  = (const float*)d_in[15];
    float* out = (float*)d_out;

    char* W = (char*)d_ws;
    ushort_t* Vbf      = (ushort_t*)(W);               // 32 MB
    float*    scoreacc = (float*)(W + 33554432);       // 512 KB
    ushort_t* probsb   = (ushort_t*)(W + 34078720);    // 64 KB (bf16)
    char* wbase = W + 34209792;
    ushort_t* Wqh = (ushort_t*)(wbase);
    ushort_t* Wql = (ushort_t*)(wbase + 32768);
    ushort_t* Wkh = (ushort_t*)(wbase + 65536);
    ushort_t* Wkl = (ushort_t*)(wbase + 98304);
    ushort_t* Wvh = (ushort_t*)(wbase + 131072);
    ushort_t* Wvl = (ushort_t*)(wbase + 163840);
    ushort_t* W1t = (ushort_t*)(wbase + 196608);       // 128 KB
    ushort_t* W2t = (ushort_t*)(wbase + 327680);       // 128 KB
    ushort_t* Wot = (ushort_t*)(wbase + 458752);       // 32 KB
    float*    G1  = (float*)(wbase + 491520);          // 2 KB
    float*    C1  = (float*)(wbase + 493568);          // 2 KB

    dim3 blk(256);
    k_wcvt<<<104, blk, 0, stream>>>(W1, W2, Wo, Wq, Wk, Wv, lng, lnb, b1,
                                    W1t, W2t, Wot, Wqh, Wql, Wkh, Wkl,
                                    Wvh, Wvl, G1, C1);
    k_qkvs<<<2048, blk, 0, stream>>>(q, v, Wqh, Wql, Wkh, Wkl, Wvh,
                                     bq, bk, bv, Vbf, scoreacc);
    k_medsoft<<<512, dim3(64), 0, stream>>>(scoreacc, probsb);
    k_tail<<<2048, blk, 0, stream>>>(Vbf, probsb, Wot, bo, W1t, G1, C1,
                                     W2t, b2, lng, lnb, v, out);
}